// Round 5
// baseline (90.324 us; speedup 1.0000x reference)
//
#include <hip/hip_runtime.h>

#define BB   4
#define NN   1024
#define DD   512
#define HH   8
#define DHH  64
#define SCALE_F 0.125f

typedef __attribute__((ext_vector_type(4))) float f32x4;
typedef __attribute__((ext_vector_type(8))) short s16x8;   // 8 bf16 (4 VGPRs)

#define MFMA16 __builtin_amdgcn_mfma_f32_16x16x32_bf16

__device__ __forceinline__ unsigned short f2bf(float f){
  union { float f; unsigned u; } v; v.f = f;
  unsigned r = v.u + 0x7FFFu + ((v.u >> 16) & 1u);   // RNE
  return (unsigned short)(r >> 16);
}
__device__ __forceinline__ float bf2f(unsigned short u){
  union { unsigned u; float f; } v; v.u = ((unsigned)u) << 16; return v.f;
}
__device__ __forceinline__ unsigned pk2(float a, float b){
  return (unsigned)f2bf(a) | ((unsigned)f2bf(b) << 16);
}
__device__ __forceinline__ void gl16(const void* g, void* l){
  __builtin_amdgcn_global_load_lds((const __attribute__((address_space(1))) unsigned int*)g,
                                   (__attribute__((address_space(3))) unsigned int*)l, 16, 0, 0);
}

// ---------------- fp32 -> bf16 conversion (vectorized) ----------------
__global__ void cvt_bf16(const float* __restrict__ src, unsigned short* __restrict__ dst, int n4){
  int i = blockIdx.x * blockDim.x + threadIdx.x;
  if (i < n4){
    float4 v = ((const float4*)src)[i];
    ushort4 o;
    o.x = f2bf(v.x); o.y = f2bf(v.y); o.z = f2bf(v.z); o.w = f2bf(v.w);
    ((ushort4*)dst)[i] = o;
  }
}

// ---------------- bias gather: biasb[h][n][m] = bf16(table[index[n][m]][h]) ----------------
__global__ void bias_gather(const float* __restrict__ table, const int* __restrict__ index,
                            unsigned short* __restrict__ biasb){
  int i = blockIdx.x * blockDim.x + threadIdx.x;   // over N*N = 1M
  int idx = index[i];
  const float4* t4 = (const float4*)table + (size_t)idx * 2;
  float4 f0 = t4[0], f1 = t4[1];
  float tv[8] = {f0.x, f0.y, f0.z, f0.w, f1.x, f1.y, f1.z, f1.w};
  #pragma unroll
  for (int h = 0; h < 8; h++){
    biasb[(h << 20) + i] = f2bf(tv[h]);
  }
}

// ---------------- GEMM1: qkv = x @ Wqkv^T; uniform [bh][tok][dh] epilogue for q/k/v ----------------
__global__ __launch_bounds__(256) void gemm_qkv(
    const unsigned short* __restrict__ A,    // xb [4096][512]
    const unsigned short* __restrict__ Bt,   // wqkvb [1536][512]
    unsigned short* __restrict__ qb, unsigned short* __restrict__ kb,
    unsigned short* __restrict__ vb)
{
  __shared__ __align__(16) unsigned short lA[128*32];
  __shared__ __align__(16) unsigned short lB[128*32];
  const int tid = threadIdx.x;
  const int lane = tid & 63;
  const int wid  = tid >> 6;
  const int i = lane & 15, g = lane >> 4;
  const int m0 = blockIdx.x * 128;
  const int n0 = blockIdx.y * 128;
  const int wr = wid >> 1, wc = wid & 1;
  const int K = 512;
  const int sr0 = wid*32 + (lane >> 2);
  const int sr1 = sr0 + 16;
  const int sc  = (lane & 3) * 8;
  const unsigned short* Ap0 = A  + (size_t)(m0 + sr0) * K + sc;
  const unsigned short* Ap1 = A  + (size_t)(m0 + sr1) * K + sc;
  const unsigned short* Bp0 = Bt + (size_t)(n0 + sr0) * K + sc;
  const unsigned short* Bp1 = Bt + (size_t)(n0 + sr1) * K + sc;
  unsigned short* lA0 = lA + sr0*32 + sc;
  unsigned short* lA1 = lA + sr1*32 + sc;
  unsigned short* lB0 = lB + sr0*32 + sc;
  unsigned short* lB1 = lB + sr1*32 + sc;

  f32x4 acc[4][4] = {};
  for (int k0 = 0; k0 < K; k0 += 32){
    gl16(Ap0 + k0, lA0);
    gl16(Ap1 + k0, lA1);
    gl16(Bp0 + k0, lB0);
    gl16(Bp1 + k0, lB1);
    __syncthreads();
    s16x8 aF[4], bF[4];
    #pragma unroll
    for (int mi = 0; mi < 4; mi++)
      aF[mi] = *(const s16x8*)(lA + (wr*64 + mi*16 + i)*32 + 8*g);
    #pragma unroll
    for (int ni = 0; ni < 4; ni++)
      bF[ni] = *(const s16x8*)(lB + (wc*64 + ni*16 + i)*32 + 8*g);
    #pragma unroll
    for (int mi = 0; mi < 4; mi++)
      #pragma unroll
      for (int ni = 0; ni < 4; ni++)
        acc[mi][ni] = MFMA16(aF[mi], bF[ni], acc[mi][ni], 0, 0, 0);
    __syncthreads();
  }
  #pragma unroll
  for (int mi = 0; mi < 4; mi++){
    #pragma unroll
    for (int r = 0; r < 4; r++){
      int row = m0 + wr*64 + mi*16 + 4*g + r;
      int b = row >> 10, tok = row & 1023;
      #pragma unroll
      for (int ni = 0; ni < 4; ni++){
        int col = n0 + wc*64 + ni*16 + i;
        unsigned short bv = f2bf(acc[mi][ni][r]);
        int part = col >> 9;
        int hh = (col >> 6) & 7;
        int dh = col & 63;
        int bh = b * 8 + hh;
        unsigned short* dst = (part == 0) ? qb : (part == 1) ? kb : vb;
        dst[((size_t)(bh << 10) + tok) * 64 + dh] = bv;
      }
    }
  }
}

// ---------------- V transpose: vb[bh][tok][dh] -> vtb[bh][chunk][dh][kk] (chunk-blocked) ----------------
__global__ __launch_bounds__(256) void v_transpose(
    const unsigned short* __restrict__ vb,
    unsigned short* __restrict__ vtb)
{
  __shared__ unsigned short t[64*65 + 8];    // stride-65 rows: column reads conflict-free
  const int tid = threadIdx.x;
  const int bh = blockIdx.x >> 4;
  const int c  = blockIdx.x & 15;
  const unsigned short* src = vb + (size_t)bh*65536 + (size_t)c*64*64;
  // phase 1: coalesced read 64 tok-rows x 64 dh, write LDS rows
  {
    int r = tid >> 2, dh0 = (tid & 3) * 16;
    s16x8 a = *(const s16x8*)(src + r*64 + dh0);
    s16x8 b = *(const s16x8*)(src + r*64 + dh0 + 8);
    #pragma unroll
    for (int u = 0; u < 8; u++) t[r*65 + dh0 + u] = (unsigned short)a[u];
    #pragma unroll
    for (int u = 0; u < 8; u++) t[r*65 + dh0 + 8 + u] = (unsigned short)b[u];
  }
  __syncthreads();
  // phase 2: column read (bank-bijective), coalesced 64B-segment writes
  {
    int dh = tid >> 2, k16 = (tid & 3) * 16;
    union { s16x8 v[2]; unsigned short u[16]; } o;
    #pragma unroll
    for (int j = 0; j < 16; j++) o.u[j] = t[(k16 + j)*65 + dh];
    unsigned short* dst = vtb + (size_t)bh*65536 + (size_t)c*4096 + dh*64 + k16;
    *(s16x8*)dst       = o.v[0];
    *(s16x8*)(dst + 8) = o.v[1];
  }
}

// ---------------- Fused flash attention v3: single-buffered bias, 3 blocks/CU ----------------
// grid: 512 blocks = (b,h,qtile64), XCD-sibling mapping; 4 waves x 16 q-rows; 16 chunks of 64 keys.
__global__ __launch_bounds__(256, 3) void attn(
    const unsigned short* __restrict__ qb,
    const unsigned short* __restrict__ kb,
    const unsigned short* __restrict__ vtb,   // [bh][16][64 dh][64 kk]
    const unsigned short* __restrict__ biasb,
    unsigned short* __restrict__ yb,
    float* __restrict__ entp, float* __restrict__ maxp)
{
  __shared__ __align__(16) unsigned short lsK[2][4096];
  __shared__ __align__(16) unsigned short lsV[2][4096];
  __shared__ __align__(16) unsigned short lsB[4096];
  __shared__ __align__(16) unsigned short lsP[4][1088];   // 68-short (136B) rows x 16
  __shared__ float sE[4], sM[4];

  const int tid = threadIdx.x, lane = tid & 63, w = tid >> 6;
  const int i = lane & 15, g = lane >> 4;
  const int sw = (i & 7) << 4;                 // xor-swizzle term (bits 4..6)

  // XCD-sibling block mapping: 4 batches of same (h,qtile) share bid%8
  const int blk = blockIdx.x;
  const int b   = (blk & 31) >> 3;
  const int grp = (blk >> 5) * 8 + (blk & 7);  // 0..127 = qt*8 + h
  const int h   = grp & 7;
  const int qt  = grp >> 3;
  const int q0  = qt * 64;
  const int bh  = b * 8 + h;

  const unsigned short* Qp = qb  + (size_t)bh * 65536;
  const unsigned short* Kp = kb  + (size_t)bh * 65536;
  const unsigned short* Vp = vtb + (size_t)bh * 65536;

  // staging slots: 512 slots of 8 shorts per 4096-short tile; wave w covers s0,s1
  const int s0 = w*64 + lane, s1 = s0 + 256;
  const int r0 = s0 >> 3,     r1 = s1 >> 3;
  const int c0 = (((s0 & 7) * 16) ^ ((r0 & 7) << 4)) >> 1;   // inverse-swizzled src col
  const int c1 = (((s1 & 7) * 16) ^ ((r1 & 7) << 4)) >> 1;
  const unsigned short* pK0 = Kp + r0*64 + c0;               // + c*4096
  const unsigned short* pK1 = Kp + r1*64 + c1;
  const unsigned short* pV0 = Vp + r0*64 + c0;               // + c*4096 (chunk-blocked)
  const unsigned short* pV1 = Vp + r1*64 + c1;
  const unsigned short* pB0 = biasb + ((size_t)(h << 10) + q0 + r0) * 1024 + c0;  // + c*64
  const unsigned short* pB1 = biasb + ((size_t)(h << 10) + q0 + r1) * 1024 + c1;

  auto STAGE_KV = [&](int bufi, int c){
    gl16(pK0 + c*4096, &lsK[bufi][0] + s0*8);
    gl16(pK1 + c*4096, &lsK[bufi][0] + s1*8);
    gl16(pV0 + c*4096, &lsV[bufi][0] + s0*8);
    gl16(pV1 + c*4096, &lsV[bufi][0] + s1*8);
  };
  auto STAGE_B = [&](int c){
    gl16(pB0 + c*64, &lsB[0] + s0*8);
    gl16(pB1 + c*64, &lsB[0] + s1*8);
  };

  // Q fragments: q-row = q0 + w*16 + i
  s16x8 qf0 = *(const s16x8*)(Qp + (size_t)(q0 + w*16 + i) * 64 + 8*g);
  s16x8 qf1 = *(const s16x8*)(Qp + (size_t)(q0 + w*16 + i) * 64 + 32 + 8*g);

  f32x4 O[4] = {};
  float m = -1e30f, l = 0.f, S1 = 0.f;

  char* Pbase = (char*)&lsP[w][0] + i*136;

  STAGE_KV(0, 0);
  STAGE_B(0);
  for (int c = 0; c < 16; ++c){
    __syncthreads();                       // sync1: prev chunk's compute fully done
    if (c < 15){
      STAGE_KV((c + 1) & 1, c + 1);
      asm volatile("s_waitcnt vmcnt(4)" ::: "memory");   // K/V/B of chunk c landed
    } else {
      asm volatile("s_waitcnt vmcnt(0)" ::: "memory");
    }
    __syncthreads();                       // sync2: all waves' staging visible

    const char* LK = (const char*)&lsK[c & 1][0];
    const char* LV = (const char*)&lsV[c & 1][0];
    const char* LB = (const char*)&lsB[0];

    // ---- QK^T over 64 keys + bias ----
    float sv[16];
    #pragma unroll
    for (int f = 0; f < 4; f++){
      s16x8 ka  = *(const s16x8*)(LK + (f*16 + i)*128 + ((16*g) ^ sw));
      s16x8 kb2 = *(const s16x8*)(LK + (f*16 + i)*128 + ((64 + 16*g) ^ sw));
      f32x4 sf = {};
      sf = MFMA16(ka,  qf0, sf, 0, 0, 0);
      sf = MFMA16(kb2, qf1, sf, 0, 0, 0);
      ushort4 bv = *(const ushort4*)(LB + (w*16 + i)*128 + ((f*32 + 8*g) ^ sw));
      sv[4*f+0] = sf[0]*SCALE_F + bf2f(bv.x);
      sv[4*f+1] = sf[1]*SCALE_F + bf2f(bv.y);
      sv[4*f+2] = sf[2]*SCALE_F + bf2f(bv.z);
      sv[4*f+3] = sf[3]*SCALE_F + bf2f(bv.w);
    }

    // ---- online softmax (lane's q-row = q0+w*16+i) ----
    float tmax = sv[0];
    #pragma unroll
    for (int j = 1; j < 16; j++) tmax = fmaxf(tmax, sv[j]);
    tmax = fmaxf(tmax, __shfl_xor(tmax, 16, 64));
    tmax = fmaxf(tmax, __shfl_xor(tmax, 32, 64));

    float m_new = fmaxf(m, tmax);
    float alpha = __expf(m - m_new);
    float e[16];
    float tl = 0.f, tS1 = 0.f;
    #pragma unroll
    for (int j = 0; j < 16; j++){
      float d = sv[j] - m_new;
      float ee = __expf(d);
      e[j] = ee; tl += ee; tS1 += ee * d;
    }
    tl  += __shfl_xor(tl, 16, 64);  tl  += __shfl_xor(tl, 32, 64);
    tS1 += __shfl_xor(tS1, 16, 64); tS1 += __shfl_xor(tS1, 32, 64);

    float l_old = l;
    S1 = alpha * (S1 + (m - m_new) * l_old) + tS1;
    l  = alpha * l_old + tl;

    if (!__all(m_new == m)){
      #pragma unroll
      for (int r = 0; r < 4; r++){
        float ar = __shfl(alpha, 4*g + r, 64);
        #pragma unroll
        for (int nf = 0; nf < 4; nf++) O[nf][r] *= ar;
      }
    }
    m = m_new;

    __syncthreads();                       // sync3: bias consumed -> safe to restage
    if (c < 15) STAGE_B(c + 1);

    // ---- P transpose via per-wave LDS ----
    #pragma unroll
    for (int f = 0; f < 4; f++){
      uint2 wp;
      wp.x = pk2(e[4*f+0], e[4*f+1]);
      wp.y = pk2(e[4*f+2], e[4*f+3]);
      *(uint2*)(Pbase + f*32 + 8*g) = wp;
    }
    asm volatile("s_waitcnt lgkmcnt(0)" ::: "memory");

    s16x8 pa0 = *(const s16x8*)(Pbase + 16*g);        // keys 8g..8g+7
    s16x8 pa1 = *(const s16x8*)(Pbase + 64 + 16*g);   // keys 32+8g..+7

    // ---- PV ----
    #pragma unroll
    for (int nf = 0; nf < 4; nf++){
      s16x8 v0 = *(const s16x8*)(LV + (nf*16 + i)*128 + ((16*g) ^ sw));
      s16x8 v1 = *(const s16x8*)(LV + (nf*16 + i)*128 + ((64 + 16*g) ^ sw));
      O[nf] = MFMA16(pa0, v0, O[nf], 0, 0, 0);
      O[nf] = MFMA16(pa1, v1, O[nf], 0, 0, 0);
    }
  }

  // ---- epilogue: normalize + write y ----
  float linv[4];
  #pragma unroll
  for (int r = 0; r < 4; r++){
    float lr = __shfl(l, 4*g + r, 64);
    linv[r] = 1.0f / lr;
  }
  #pragma unroll
  for (int nf = 0; nf < 4; nf++){
    #pragma unroll
    for (int r = 0; r < 4; r++){
      int row = q0 + w*16 + 4*g + r;
      int col = h*64 + nf*16 + i;
      yb[((size_t)(b << 10) + row) * 512 + col] = f2bf(O[nf][r] * linv[r]);
    }
  }

  // ---- stats ----
  float ent = __logf(l) - S1 / l;
  float esum = (g == 0) ? ent : 0.f;
  float wmax = 1.0f / l;
  #pragma unroll
  for (int off = 1; off < 64; off <<= 1){
    esum += __shfl_xor(esum, off, 64);
    wmax = fmaxf(wmax, __shfl_xor(wmax, off, 64));
  }
  if (lane == 0){ sE[w] = esum; sM[w] = wmax; }
  __syncthreads();
  if (tid == 0){
    entp[blk] = sE[0] + sE[1] + sE[2] + sE[3];
    maxp[blk] = fmaxf(fmaxf(sM[0], sM[1]), fmaxf(sM[2], sM[3]));
  }
}

// ---------------- GEMM2: out = y @ Wproj^T (fp32 out) ----------------
__global__ __launch_bounds__(256) void gemm_proj(
    const unsigned short* __restrict__ A,   // yb [4096][512]
    const unsigned short* __restrict__ Bt,  // wprojb [512][512]
    float* __restrict__ out)
{
  __shared__ __align__(16) unsigned short lA[128*32];
  __shared__ __align__(16) unsigned short lB[128*32];
  const int tid = threadIdx.x;
  const int lane = tid & 63;
  const int wid  = tid >> 6;
  const int i = lane & 15, g = lane >> 4;
  const int m0 = blockIdx.x * 128;
  const int n0 = blockIdx.y * 128;
  const int wr = wid >> 1, wc = wid & 1;
  const int K = 512;
  const int sr0 = wid*32 + (lane >> 2);
  const int sr1 = sr0 + 16;
  const int sc  = (lane & 3) * 8;
  const unsigned short* Ap0 = A  + (size_t)(m0 + sr0) * K + sc;
  const unsigned short* Ap1 = A  + (size_t)(m0 + sr1) * K + sc;
  const unsigned short* Bp0 = Bt + (size_t)(n0 + sr0) * K + sc;
  const unsigned short* Bp1 = Bt + (size_t)(n0 + sr1) * K + sc;
  unsigned short* lA0 = lA + sr0*32 + sc;
  unsigned short* lA1 = lA + sr1*32 + sc;
  unsigned short* lB0 = lB + sr0*32 + sc;
  unsigned short* lB1 = lB + sr1*32 + sc;

  f32x4 acc[4][4] = {};
  for (int k0 = 0; k0 < K; k0 += 32){
    gl16(Ap0 + k0, lA0);
    gl16(Ap1 + k0, lA1);
    gl16(Bp0 + k0, lB0);
    gl16(Bp1 + k0, lB1);
    __syncthreads();
    s16x8 aF[4], bF[4];
    #pragma unroll
    for (int mi = 0; mi < 4; mi++)
      aF[mi] = *(const s16x8*)(lA + (wr*64 + mi*16 + i)*32 + 8*g);
    #pragma unroll
    for (int ni = 0; ni < 4; ni++)
      bF[ni] = *(const s16x8*)(lB + (wc*64 + ni*16 + i)*32 + 8*g);
    #pragma unroll
    for (int mi = 0; mi < 4; mi++)
      #pragma unroll
      for (int ni = 0; ni < 4; ni++)
        acc[mi][ni] = MFMA16(aF[mi], bF[ni], acc[mi][ni], 0, 0, 0);
    __syncthreads();
  }
  #pragma unroll
  for (int mi = 0; mi < 4; mi++){
    #pragma unroll
    for (int r = 0; r < 4; r++){
      int row = m0 + wr*64 + mi*16 + 4*g + r;
      #pragma unroll
      for (int ni = 0; ni < 4; ni++){
        int col = n0 + wc*64 + ni*16 + i;
        out[(size_t)row * 512 + col] = acc[mi][ni][r];
      }
    }
  }
}

// ---------------- finalize scalars ----------------
__global__ void finalize(const float* __restrict__ entp, const float* __restrict__ maxp,
                         float* __restrict__ o){
  int lane = threadIdx.x;   // 64 threads
  float e = 0.f, mx = -1e30f;
  for (int j = lane; j < 512; j += 64){
    e += entp[j];
    mx = fmaxf(mx, maxp[j]);
  }
  #pragma unroll
  for (int off = 1; off < 64; off <<= 1){
    e += __shfl_xor(e, off, 64);
    mx = fmaxf(mx, __shfl_xor(mx, off, 64));
  }
  if (lane == 0){
    o[0] = e / 32768.0f;       // mean entropy over B*H*N rows
    o[1] = mx;                 // amax
    o[2] = 1.0f / 1024.0f;     // amean (rows sum to 1)
  }
}

extern "C" void kernel_launch(void* const* d_in, const int* in_sizes, int n_in,
                              void* d_out, int out_size, void* d_ws, size_t ws_size,
                              hipStream_t stream){
  const float* x     = (const float*)d_in[0];
  const float* Wqkv  = (const float*)d_in[1];
  const float* Wproj = (const float*)d_in[2];
  const float* table = (const float*)d_in[3];
  const int*   index = (const int*)d_in[4];
  float* out = (float*)d_out;
  char* ws = (char*)d_ws;

  unsigned short* xb     = (unsigned short*)(ws + 0);          //  4 MB
  unsigned short* wqkvb  = (unsigned short*)(ws + 4194304);    //  1.5 MB
  unsigned short* wprojb = (unsigned short*)(ws + 5767168);    //  0.5 MB
  unsigned short* qb     = (unsigned short*)(ws + 6291456);    //  4 MB
  unsigned short* kb     = (unsigned short*)(ws + 10485760);   //  4 MB
  unsigned short* vtb    = (unsigned short*)(ws + 14680064);   //  4 MB
  unsigned short* yb     = (unsigned short*)(ws + 18874368);   //  4 MB
  unsigned short* biasb  = (unsigned short*)(ws + 23068672);   // 16 MB
  float* entp            = (float*)(ws + 39845888);            //  2 KB
  float* maxp            = (float*)(ws + 39847936);            //  2 KB
  unsigned short* vb     = (unsigned short*)(ws + 41943040);   //  4 MB (natural-layout V)

  cvt_bf16<<<2048, 256, 0, stream>>>(x, xb, 524288);
  cvt_bf16<<<768, 256, 0, stream>>>(Wqkv, wqkvb, 196608);
  cvt_bf16<<<256, 256, 0, stream>>>(Wproj, wprojb, 65536);
  bias_gather<<<4096, 256, 0, stream>>>(table, index, biasb);
  gemm_qkv<<<dim3(32, 12), 256, 0, stream>>>(xb, wqkvb, qb, kb, vb);
  v_transpose<<<512, 256, 0, stream>>>(vb, vtb);
  attn<<<512, 256, 0, stream>>>(qb, kb, vtb, biasb, yb, entp, maxp);
  gemm_proj<<<dim3(32, 4), 256, 0, stream>>>(yb, wprojb, out);
  finalize<<<1, 64, 0, stream>>>(entp, maxp, out + 2097152);
}

// Round 6
// 79.177 us; speedup vs baseline: 1.1408x; 1.1408x over previous
//
#include <hip/hip_runtime.h>

#define BB   4
#define NN   1024
#define DD   512
#define HH   8
#define DHH  64
#define SCALE2  0.180336880f     // 0.125 * log2(e)  -> scores in log2 units
#define LOG2E   1.44269504089f
#define LN2     0.69314718056f

typedef __attribute__((ext_vector_type(4))) float f32x4;
typedef __attribute__((ext_vector_type(8))) short s16x8;   // 8 bf16 (4 VGPRs)

#define MFMA16 __builtin_amdgcn_mfma_f32_16x16x32_bf16

__device__ __forceinline__ unsigned short f2bf(float f){
  union { float f; unsigned u; } v; v.f = f;
  unsigned r = v.u + 0x7FFFu + ((v.u >> 16) & 1u);   // RNE
  return (unsigned short)(r >> 16);
}
__device__ __forceinline__ float bf2f(unsigned short u){
  union { unsigned u; float f; } v; v.u = ((unsigned)u) << 16; return v.f;
}
// truncating bf16 pack of (a,b) -> one dword via v_perm (1 instr)
__device__ __forceinline__ unsigned pk2t(float a, float b){
  return __builtin_amdgcn_perm(__float_as_uint(b), __float_as_uint(a), 0x07060302u);
}
__device__ __forceinline__ void gl16(const void* g, void* l){
  __builtin_amdgcn_global_load_lds((const __attribute__((address_space(1))) unsigned int*)g,
                                   (__attribute__((address_space(3))) unsigned int*)l, 16, 0, 0);
}

// ---------------- fused fp32 -> bf16 conversion for x, Wqkv, Wproj ----------------
__global__ void cvt_all(const float* __restrict__ x, const float* __restrict__ wq,
                        const float* __restrict__ wp,
                        unsigned short* __restrict__ xb, unsigned short* __restrict__ wqb,
                        unsigned short* __restrict__ wpb){
  int idx = blockIdx.x * blockDim.x + threadIdx.x;   // 786432 float4 total
  const float4* s; ushort4* d; int j;
  if (idx < 524288){ s = (const float4*)x;  d = (ushort4*)xb;  j = idx; }
  else if (idx < 720896){ s = (const float4*)wq; d = (ushort4*)wqb; j = idx - 524288; }
  else { s = (const float4*)wp; d = (ushort4*)wpb; j = idx - 720896; }
  float4 v = s[j];
  ushort4 o;
  o.x = f2bf(v.x); o.y = f2bf(v.y); o.z = f2bf(v.z); o.w = f2bf(v.w);
  d[j] = o;
}

// ---------------- bias gather (pre-scaled by log2e): biasb[h][n][m] ----------------
__global__ void bias_gather(const float* __restrict__ table, const int* __restrict__ index,
                            unsigned short* __restrict__ biasb){
  int i = blockIdx.x * blockDim.x + threadIdx.x;   // over N*N = 1M
  int idx = index[i];
  const float4* t4 = (const float4*)table + (size_t)idx * 2;
  float4 f0 = t4[0], f1 = t4[1];
  float tv[8] = {f0.x, f0.y, f0.z, f0.w, f1.x, f1.y, f1.z, f1.w};
  #pragma unroll
  for (int h = 0; h < 8; h++){
    biasb[(h << 20) + i] = f2bf(tv[h] * LOG2E);
  }
}

// ---------------- GEMM1: qkv = x @ Wqkv^T, 64x128 tile, grid 768 = 3/CU ----------------
__global__ __launch_bounds__(256) void gemm_qkv(
    const unsigned short* __restrict__ A,    // xb [4096][512]
    const unsigned short* __restrict__ Bt,   // wqkvb [1536][512]
    unsigned short* __restrict__ qb, unsigned short* __restrict__ kb,
    unsigned short* __restrict__ vb)
{
  __shared__ __align__(16) unsigned short lA[64*32];
  __shared__ __align__(16) unsigned short lB[128*32];
  const int tid = threadIdx.x;
  const int lane = tid & 63;
  const int wid  = tid >> 6;
  const int i = lane & 15, g = lane >> 4;
  const int m0 = blockIdx.x * 64;
  const int n0 = blockIdx.y * 128;
  const int wr = wid >> 1, wc = wid & 1;   // wave tile 32 x 64
  const int K = 512;
  const int srA = tid >> 2;                // 0..63
  const int scc = (tid & 3) * 8;
  const unsigned short* ApS  = A  + (size_t)(m0 + srA) * K + scc;
  const unsigned short* BpS0 = Bt + (size_t)(n0 + srA) * K + scc;
  const unsigned short* BpS1 = Bt + (size_t)(n0 + 64 + srA) * K + scc;
  unsigned short* lAs  = lA + srA*32 + scc;
  unsigned short* lBs0 = lB + srA*32 + scc;
  unsigned short* lBs1 = lB + (64 + srA)*32 + scc;

  f32x4 acc[2][4] = {};
  for (int k0 = 0; k0 < K; k0 += 32){
    gl16(ApS + k0, lAs);
    gl16(BpS0 + k0, lBs0);
    gl16(BpS1 + k0, lBs1);
    __syncthreads();
    s16x8 aF[2], bF[4];
    #pragma unroll
    for (int mi = 0; mi < 2; mi++)
      aF[mi] = *(const s16x8*)(lA + (wr*32 + mi*16 + i)*32 + 8*g);
    #pragma unroll
    for (int ni = 0; ni < 4; ni++)
      bF[ni] = *(const s16x8*)(lB + (wc*64 + ni*16 + i)*32 + 8*g);
    #pragma unroll
    for (int mi = 0; mi < 2; mi++)
      #pragma unroll
      for (int ni = 0; ni < 4; ni++)
        acc[mi][ni] = MFMA16(aF[mi], bF[ni], acc[mi][ni], 0, 0, 0);
    __syncthreads();
  }
  #pragma unroll
  for (int mi = 0; mi < 2; mi++){
    #pragma unroll
    for (int r = 0; r < 4; r++){
      int row = m0 + wr*32 + mi*16 + 4*g + r;
      int b = row >> 10, tok = row & 1023;
      #pragma unroll
      for (int ni = 0; ni < 4; ni++){
        int col = n0 + wc*64 + ni*16 + i;
        unsigned short bv = f2bf(acc[mi][ni][r]);
        int part = col >> 9;
        int hh = (col >> 6) & 7;
        int dh = col & 63;
        int bh = b * 8 + hh;
        unsigned short* dst = (part == 0) ? qb : (part == 1) ? kb : vb;
        dst[((size_t)(bh << 10) + tok) * 64 + dh] = bv;
      }
    }
  }
}

// ---------------- V transpose: vb[bh][tok][dh] -> vtb[bh][chunk][dh 64][kk 64] ----------------
__global__ __launch_bounds__(256) void v_transpose(
    const unsigned short* __restrict__ vb,
    unsigned short* __restrict__ vtb)
{
  __shared__ unsigned short t[64*65 + 8];
  const int tid = threadIdx.x;
  const int bh = blockIdx.x >> 4;
  const int c  = blockIdx.x & 15;
  const unsigned short* src = vb + (size_t)bh*65536 + (size_t)c*64*64;
  {
    int r = tid >> 2, dh0 = (tid & 3) * 16;
    s16x8 a = *(const s16x8*)(src + r*64 + dh0);
    s16x8 b = *(const s16x8*)(src + r*64 + dh0 + 8);
    #pragma unroll
    for (int u = 0; u < 8; u++) t[r*65 + dh0 + u] = (unsigned short)a[u];
    #pragma unroll
    for (int u = 0; u < 8; u++) t[r*65 + dh0 + 8 + u] = (unsigned short)b[u];
  }
  __syncthreads();
  {
    int dh = tid >> 2, k16 = (tid & 3) * 16;
    union { s16x8 v[2]; unsigned short u[16]; } o;
    #pragma unroll
    for (int j = 0; j < 16; j++) o.u[j] = t[(k16 + j)*65 + dh];
    unsigned short* dst = vtb + (size_t)bh*65536 + (size_t)c*4096 + dh*64 + k16;
    *(s16x8*)dst       = o.v[0];
    *(s16x8*)(dst + 8) = o.v[1];
  }
}

// ---------------- Fused flash attention v4: R4 structure + log2 units + defer-max ----------------
// grid: 512 blocks = (b,h,qtile64), XCD-sibling mapping; 4 waves x 16 q-rows; 16 chunks of 64 keys.
__global__ __launch_bounds__(256, 2) void attn(
    const unsigned short* __restrict__ qb,
    const unsigned short* __restrict__ kb,
    const unsigned short* __restrict__ vtb,   // [bh][16][64 dh][64 kk]
    const unsigned short* __restrict__ biasb, // log2e-scaled
    unsigned short* __restrict__ yb,
    float* __restrict__ entp, float* __restrict__ maxp)
{
  __shared__ __align__(16) unsigned short lsK[2][4096];
  __shared__ __align__(16) unsigned short lsV[2][4096];
  __shared__ __align__(16) unsigned short lsB[2][4096];
  __shared__ __align__(16) unsigned short lsP[4][1088];   // 16 rows x 68 shorts (136B)
  __shared__ float sE[4], sM[4];

  const int tid = threadIdx.x, lane = tid & 63, w = tid >> 6;
  const int i = lane & 15, g = lane >> 4;
  const int sw = (i & 7) << 4;

  const int blk = blockIdx.x;
  const int b   = (blk & 31) >> 3;
  const int grp = (blk >> 5) * 8 + (blk & 7);  // qt*8 + h
  const int h   = grp & 7;
  const int qt  = grp >> 3;
  const int q0  = qt * 64;
  const int bh  = b * 8 + h;

  const unsigned short* Qp = qb  + (size_t)bh * 65536;
  const unsigned short* Kp = kb  + (size_t)bh * 65536;
  const unsigned short* Vp = vtb + (size_t)bh * 65536;

  const int s0 = w*64 + lane, s1 = s0 + 256;
  const int r0 = s0 >> 3,     r1 = s1 >> 3;
  const int c0 = (((s0 & 7) * 16) ^ ((r0 & 7) << 4)) >> 1;
  const int c1 = (((s1 & 7) * 16) ^ ((r1 & 7) << 4)) >> 1;
  const unsigned short* pK0 = Kp + r0*64 + c0;
  const unsigned short* pK1 = Kp + r1*64 + c1;
  const unsigned short* pV0 = Vp + r0*64 + c0;
  const unsigned short* pV1 = Vp + r1*64 + c1;
  const unsigned short* pB0 = biasb + ((size_t)(h << 10) + q0 + r0) * 1024 + c0;
  const unsigned short* pB1 = biasb + ((size_t)(h << 10) + q0 + r1) * 1024 + c1;

  auto STAGE = [&](int bufi, int c){
    gl16(pK0 + c*4096, &lsK[bufi][0] + s0*8);
    gl16(pK1 + c*4096, &lsK[bufi][0] + s1*8);
    gl16(pV0 + c*4096, &lsV[bufi][0] + s0*8);
    gl16(pV1 + c*4096, &lsV[bufi][0] + s1*8);
    gl16(pB0 + c*64,   &lsB[bufi][0] + s0*8);
    gl16(pB1 + c*64,   &lsB[bufi][0] + s1*8);
  };

  s16x8 qf0 = *(const s16x8*)(Qp + (size_t)(q0 + w*16 + i) * 64 + 8*g);
  s16x8 qf1 = *(const s16x8*)(Qp + (size_t)(q0 + w*16 + i) * 64 + 32 + 8*g);

  f32x4 O[4] = {};
  float m = -1e30f, l = 0.f, S1 = 0.f, emax = 0.f;

  char* Pbase = (char*)&lsP[w][0] + i*136;

  STAGE(0, 0);
  for (int c = 0; c < 16; ++c){
    __syncthreads();
    if (c < 15){
      STAGE((c + 1) & 1, c + 1);
      asm volatile("s_waitcnt vmcnt(6)" ::: "memory");
    } else {
      asm volatile("s_waitcnt vmcnt(0)" ::: "memory");
    }
    __syncthreads();

    const char* LK = (const char*)&lsK[c & 1][0];
    const char* LV = (const char*)&lsV[c & 1][0];
    const char* LB = (const char*)&lsB[c & 1][0];

    // ---- QK^T over 64 keys + bias (log2 units) ----
    float sv[16];
    #pragma unroll
    for (int f = 0; f < 4; f++){
      s16x8 ka  = *(const s16x8*)(LK + (f*16 + i)*128 + ((16*g) ^ sw));
      s16x8 kb2 = *(const s16x8*)(LK + (f*16 + i)*128 + ((64 + 16*g) ^ sw));
      f32x4 sf = {};
      sf = MFMA16(ka,  qf0, sf, 0, 0, 0);
      sf = MFMA16(kb2, qf1, sf, 0, 0, 0);
      ushort4 bv = *(const ushort4*)(LB + (w*16 + i)*128 + ((f*32 + 8*g) ^ sw));
      sv[4*f+0] = sf[0]*SCALE2 + bf2f(bv.x);
      sv[4*f+1] = sf[1]*SCALE2 + bf2f(bv.y);
      sv[4*f+2] = sf[2]*SCALE2 + bf2f(bv.z);
      sv[4*f+3] = sf[3]*SCALE2 + bf2f(bv.w);
    }

    // ---- max tree (depth 4, clang fuses to v_max3) + cross-g ----
    float t0 = fmaxf(fmaxf(sv[0],  sv[1]),  sv[2]);
    float t1 = fmaxf(fmaxf(sv[3],  sv[4]),  sv[5]);
    float t2 = fmaxf(fmaxf(sv[6],  sv[7]),  sv[8]);
    float t3 = fmaxf(fmaxf(sv[9],  sv[10]), sv[11]);
    float t4 = fmaxf(fmaxf(sv[12], sv[13]), sv[14]);
    float tmax = fmaxf(fmaxf(fmaxf(t0, t1), fmaxf(t2, t3)), fmaxf(t4, sv[15]));
    tmax = fmaxf(tmax, __shfl_xor(tmax, 16, 64));
    tmax = fmaxf(tmax, __shfl_xor(tmax, 32, 64));

    // ---- T13 defer-max: only rescale when growth > 8 (log2 units) ----
    if (!__all(tmax - m <= 8.0f)){
      float m_new = fmaxf(m, tmax);
      float alpha = exp2f(m - m_new);
      S1 = alpha * (S1 + (m - m_new) * l);
      l *= alpha;
      emax *= alpha;
      #pragma unroll
      for (int r = 0; r < 4; r++){
        float ar = __shfl(alpha, 4*g + r, 64);
        #pragma unroll
        for (int nf = 0; nf < 4; nf++) O[nf][r] *= ar;
      }
      m = m_new;
    }

    float e[16];
    float tl = 0.f, tS1 = 0.f;
    #pragma unroll
    for (int j = 0; j < 16; j++){
      float d = sv[j] - m;
      float ee = exp2f(d);
      e[j] = ee; tl += ee; tS1 += ee * d;
    }
    tl  += __shfl_xor(tl, 16, 64);  tl  += __shfl_xor(tl, 32, 64);
    tS1 += __shfl_xor(tS1, 16, 64); tS1 += __shfl_xor(tS1, 32, 64);
    S1 += tS1;
    l  += tl;
    emax = fmaxf(emax, exp2f(tmax - m));

    // ---- P transpose via per-wave LDS (truncating v_perm pack) ----
    #pragma unroll
    for (int f = 0; f < 4; f++){
      uint2 wp;
      wp.x = pk2t(e[4*f+0], e[4*f+1]);
      wp.y = pk2t(e[4*f+2], e[4*f+3]);
      *(uint2*)(Pbase + f*32 + 8*g) = wp;
    }
    asm volatile("s_waitcnt lgkmcnt(0)" ::: "memory");

    s16x8 pa0 = *(const s16x8*)(Pbase + 16*g);
    s16x8 pa1 = *(const s16x8*)(Pbase + 64 + 16*g);

    // ---- PV ----
    #pragma unroll
    for (int nf = 0; nf < 4; nf++){
      s16x8 v0 = *(const s16x8*)(LV + (nf*16 + i)*128 + ((16*g) ^ sw));
      s16x8 v1 = *(const s16x8*)(LV + (nf*16 + i)*128 + ((64 + 16*g) ^ sw));
      O[nf] = MFMA16(pa0, v0, O[nf], 0, 0, 0);
      O[nf] = MFMA16(pa1, v1, O[nf], 0, 0, 0);
    }
  }

  // ---- epilogue: normalize + write y ----
  float linv[4];
  #pragma unroll
  for (int r = 0; r < 4; r++){
    float lr = __shfl(l, 4*g + r, 64);
    linv[r] = 1.0f / lr;
  }
  #pragma unroll
  for (int nf = 0; nf < 4; nf++){
    #pragma unroll
    for (int r = 0; r < 4; r++){
      int row = q0 + w*16 + 4*g + r;
      int col = h*64 + nf*16 + i;
      yb[((size_t)(b << 10) + row) * 512 + col] = f2bf(O[nf][r] * linv[r]);
    }
  }

  // ---- stats: ent = ln(l) - ln2*S1/l ; pmax = emax/l ----
  float ent = __logf(l) - LN2 * S1 / l;
  float esum = (g == 0) ? ent : 0.f;
  float wmax = emax / l;
  #pragma unroll
  for (int off = 1; off < 64; off <<= 1){
    esum += __shfl_xor(esum, off, 64);
    wmax = fmaxf(wmax, __shfl_xor(wmax, off, 64));
  }
  if (lane == 0){ sE[w] = esum; sM[w] = wmax; }
  __syncthreads();
  if (tid == 0){
    entp[blk] = sE[0] + sE[1] + sE[2] + sE[3];
    maxp[blk] = fmaxf(fmaxf(sM[0], sM[1]), fmaxf(sM[2], sM[3]));
  }
}

// ---------------- GEMM2: out = y @ Wproj^T, 64x64 tile, grid 512 = 2/CU (fp32 out) ----------------
__global__ __launch_bounds__(256) void gemm_proj(
    const unsigned short* __restrict__ A,   // yb [4096][512]
    const unsigned short* __restrict__ Bt,  // wprojb [512][512]
    float* __restrict__ out)
{
  __shared__ __align__(16) unsigned short lA[64*32];
  __shared__ __align__(16) unsigned short lB[64*32];
  const int tid = threadIdx.x;
  const int lane = tid & 63;
  const int wid  = tid >> 6;
  const int i = lane & 15, g = lane >> 4;
  const int m0 = blockIdx.x * 64;
  const int n0 = blockIdx.y * 64;
  const int wr = wid >> 1, wc = wid & 1;   // wave tile 32 x 32
  const int K = 512;
  const int srA = tid >> 2;
  const int scc = (tid & 3) * 8;
  const unsigned short* ApS = A  + (size_t)(m0 + srA) * K + scc;
  const unsigned short* BpS = Bt + (size_t)(n0 + srA) * K + scc;
  unsigned short* lAs = lA + srA*32 + scc;
  unsigned short* lBs = lB + srA*32 + scc;

  f32x4 acc[2][2] = {};
  for (int k0 = 0; k0 < K; k0 += 32){
    gl16(ApS + k0, lAs);
    gl16(BpS + k0, lBs);
    __syncthreads();
    s16x8 aF[2], bF[2];
    #pragma unroll
    for (int mi = 0; mi < 2; mi++)
      aF[mi] = *(const s16x8*)(lA + (wr*32 + mi*16 + i)*32 + 8*g);
    #pragma unroll
    for (int ni = 0; ni < 2; ni++)
      bF[ni] = *(const s16x8*)(lB + (wc*32 + ni*16 + i)*32 + 8*g);
    #pragma unroll
    for (int mi = 0; mi < 2; mi++)
      #pragma unroll
      for (int ni = 0; ni < 2; ni++)
        acc[mi][ni] = MFMA16(aF[mi], bF[ni], acc[mi][ni], 0, 0, 0);
    __syncthreads();
  }
  #pragma unroll
  for (int mi = 0; mi < 2; mi++){
    #pragma unroll
    for (int r = 0; r < 4; r++){
      int row = m0 + wr*32 + mi*16 + 4*g + r;
      #pragma unroll
      for (int ni = 0; ni < 2; ni++){
        int col = n0 + wc*32 + ni*16 + i;
        out[(size_t)row * 512 + col] = acc[mi][ni][r];
      }
    }
  }
}

// ---------------- finalize scalars ----------------
__global__ void finalize(const float* __restrict__ entp, const float* __restrict__ maxp,
                         float* __restrict__ o){
  int lane = threadIdx.x;   // 64 threads
  float e = 0.f, mx = -1e30f;
  for (int j = lane; j < 512; j += 64){
    e += entp[j];
    mx = fmaxf(mx, maxp[j]);
  }
  #pragma unroll
  for (int off = 1; off < 64; off <<= 1){
    e += __shfl_xor(e, off, 64);
    mx = fmaxf(mx, __shfl_xor(mx, off, 64));
  }
  if (lane == 0){
    o[0] = e / 32768.0f;       // mean entropy over B*H*N rows
    o[1] = mx;                 // amax
    o[2] = 1.0f / 1024.0f;     // amean (rows sum to 1)
  }
}

extern "C" void kernel_launch(void* const* d_in, const int* in_sizes, int n_in,
                              void* d_out, int out_size, void* d_ws, size_t ws_size,
                              hipStream_t stream){
  const float* x     = (const float*)d_in[0];
  const float* Wqkv  = (const float*)d_in[1];
  const float* Wproj = (const float*)d_in[2];
  const float* table = (const float*)d_in[3];
  const int*   index = (const int*)d_in[4];
  float* out = (float*)d_out;
  char* ws = (char*)d_ws;

  unsigned short* xb     = (unsigned short*)(ws + 0);          //  4 MB
  unsigned short* wqkvb  = (unsigned short*)(ws + 4194304);    //  1.5 MB
  unsigned short* wprojb = (unsigned short*)(ws + 5767168);    //  0.5 MB
  unsigned short* qb     = (unsigned short*)(ws + 6291456);    //  4 MB
  unsigned short* kb     = (unsigned short*)(ws + 10485760);   //  4 MB
  unsigned short* vtb    = (unsigned short*)(ws + 14680064);   //  4 MB
  unsigned short* yb     = (unsigned short*)(ws + 18874368);   //  4 MB
  unsigned short* biasb  = (unsigned short*)(ws + 23068672);   // 16 MB
  float* entp            = (float*)(ws + 39845888);            //  2 KB
  float* maxp            = (float*)(ws + 39847936);            //  2 KB
  unsigned short* vb     = (unsigned short*)(ws + 41943040);   //  4 MB (natural-layout V)

  cvt_all<<<3072, 256, 0, stream>>>(x, Wqkv, Wproj, xb, wqkvb, wprojb);
  bias_gather<<<4096, 256, 0, stream>>>(table, index, biasb);
  gemm_qkv<<<dim3(64, 12), 256, 0, stream>>>(xb, wqkvb, qb, kb, vb);
  v_transpose<<<512, 256, 0, stream>>>(vb, vtb);
  attn<<<512, 256, 0, stream>>>(qb, kb, vtb, biasb, yb, entp, maxp);
  gemm_proj<<<dim3(64, 8), 256, 0, stream>>>(yb, wprojb, out);
  finalize<<<1, 64, 0, stream>>>(entp, maxp, out + 2097152);
}

// Round 7
// 77.897 us; speedup vs baseline: 1.1595x; 1.0164x over previous
//
#include <hip/hip_runtime.h>

#define BB   4
#define NN   1024
#define DD   512
#define HH   8
#define DHH  64
#define SCALE2  0.180336880f     // 0.125 * log2(e)  -> scores in log2 units
#define LOG2E   1.44269504089f
#define LN2     0.69314718056f

typedef __attribute__((ext_vector_type(4))) float f32x4;
typedef __attribute__((ext_vector_type(8))) short s16x8;   // 8 bf16 (4 VGPRs)

#define MFMA16 __builtin_amdgcn_mfma_f32_16x16x32_bf16

__device__ __forceinline__ unsigned short f2bf(float f){
  union { float f; unsigned u; } v; v.f = f;
  unsigned r = v.u + 0x7FFFu + ((v.u >> 16) & 1u);   // RNE
  return (unsigned short)(r >> 16);
}
__device__ __forceinline__ float bf2f(unsigned short u){
  union { unsigned u; float f; } v; v.u = ((unsigned)u) << 16; return v.f;
}
// truncating bf16 pack of (a,b) -> one dword via v_perm (1 instr)
__device__ __forceinline__ unsigned pk2t(float a, float b){
  return __builtin_amdgcn_perm(__float_as_uint(b), __float_as_uint(a), 0x07060302u);
}
__device__ __forceinline__ void gl16(const void* g, void* l){
  __builtin_amdgcn_global_load_lds((const __attribute__((address_space(1))) unsigned int*)g,
                                   (__attribute__((address_space(3))) unsigned int*)l, 16, 0, 0);
}

// ------- fused fp32->bf16: x, Wqkv, Wproj, and relpos table (transposed, log2e-scaled) -------
__global__ void cvt_all(const float* __restrict__ x, const float* __restrict__ wq,
                        const float* __restrict__ wp, const float* __restrict__ table,
                        unsigned short* __restrict__ xb, unsigned short* __restrict__ wqb,
                        unsigned short* __restrict__ wpb, unsigned short* __restrict__ tableb){
  int idx = blockIdx.x * blockDim.x + threadIdx.x;
  if (idx < 786432){
    const float4* s; ushort4* d; int j;
    if (idx < 524288){ s = (const float4*)x;  d = (ushort4*)xb;  j = idx; }
    else if (idx < 720896){ s = (const float4*)wq; d = (ushort4*)wqb; j = idx - 524288; }
    else { s = (const float4*)wp; d = (ushort4*)wpb; j = idx - 720896; }
    float4 v = s[j];
    ushort4 o;
    o.x = f2bf(v.x); o.y = f2bf(v.y); o.z = f2bf(v.z); o.w = f2bf(v.w);
    d[j] = o;
  } else {
    int j = idx - 786432;            // 0..4095 ; table is [3969][8]
    float tv[8] = {0,0,0,0,0,0,0,0};
    if (j < 3969){
      const float4* t4 = (const float4*)table + (size_t)j * 2;
      float4 f0 = t4[0], f1 = t4[1];
      tv[0]=f0.x; tv[1]=f0.y; tv[2]=f0.z; tv[3]=f0.w;
      tv[4]=f1.x; tv[5]=f1.y; tv[6]=f1.z; tv[7]=f1.w;
    }
    #pragma unroll
    for (int h = 0; h < 8; h++)
      tableb[(h << 12) + j] = f2bf(tv[h] * LOG2E);
  }
}

// ---------------- GEMM1: qkv = x @ Wqkv^T, 64x128 tile, grid 768 = 3/CU ----------------
__global__ __launch_bounds__(256) void gemm_qkv(
    const unsigned short* __restrict__ A,    // xb [4096][512]
    const unsigned short* __restrict__ Bt,   // wqkvb [1536][512]
    unsigned short* __restrict__ qb, unsigned short* __restrict__ kb,
    unsigned short* __restrict__ vb)
{
  __shared__ __align__(16) unsigned short lA[64*32];
  __shared__ __align__(16) unsigned short lB[128*32];
  const int tid = threadIdx.x;
  const int lane = tid & 63;
  const int wid  = tid >> 6;
  const int i = lane & 15, g = lane >> 4;
  const int m0 = blockIdx.x * 64;
  const int n0 = blockIdx.y * 128;
  const int wr = wid >> 1, wc = wid & 1;   // wave tile 32 x 64
  const int K = 512;
  const int srA = tid >> 2;                // 0..63
  const int scc = (tid & 3) * 8;
  const unsigned short* ApS  = A  + (size_t)(m0 + srA) * K + scc;
  const unsigned short* BpS0 = Bt + (size_t)(n0 + srA) * K + scc;
  const unsigned short* BpS1 = Bt + (size_t)(n0 + 64 + srA) * K + scc;
  unsigned short* lAs  = lA + srA*32 + scc;
  unsigned short* lBs0 = lB + srA*32 + scc;
  unsigned short* lBs1 = lB + (64 + srA)*32 + scc;

  f32x4 acc[2][4] = {};
  for (int k0 = 0; k0 < K; k0 += 32){
    gl16(ApS + k0, lAs);
    gl16(BpS0 + k0, lBs0);
    gl16(BpS1 + k0, lBs1);
    __syncthreads();
    s16x8 aF[2], bF[4];
    #pragma unroll
    for (int mi = 0; mi < 2; mi++)
      aF[mi] = *(const s16x8*)(lA + (wr*32 + mi*16 + i)*32 + 8*g);
    #pragma unroll
    for (int ni = 0; ni < 4; ni++)
      bF[ni] = *(const s16x8*)(lB + (wc*64 + ni*16 + i)*32 + 8*g);
    #pragma unroll
    for (int mi = 0; mi < 2; mi++)
      #pragma unroll
      for (int ni = 0; ni < 4; ni++)
        acc[mi][ni] = MFMA16(aF[mi], bF[ni], acc[mi][ni], 0, 0, 0);
    __syncthreads();
  }
  #pragma unroll
  for (int mi = 0; mi < 2; mi++){
    #pragma unroll
    for (int r = 0; r < 4; r++){
      int row = m0 + wr*32 + mi*16 + 4*g + r;
      int b = row >> 10, tok = row & 1023;
      #pragma unroll
      for (int ni = 0; ni < 4; ni++){
        int col = n0 + wc*64 + ni*16 + i;
        unsigned short bv = f2bf(acc[mi][ni][r]);
        int part = col >> 9;
        int hh = (col >> 6) & 7;
        int dh = col & 63;
        int bh = b * 8 + hh;
        unsigned short* dst = (part == 0) ? qb : (part == 1) ? kb : vb;
        dst[((size_t)(bh << 10) + tok) * 64 + dh] = bv;
      }
    }
  }
}

// ---------------- V transpose: vb[bh][tok][dh] -> vtb[bh][chunk][dh 64][kk 64] ----------------
__global__ __launch_bounds__(256) void v_transpose(
    const unsigned short* __restrict__ vb,
    unsigned short* __restrict__ vtb)
{
  __shared__ unsigned short t[64*65 + 8];
  const int tid = threadIdx.x;
  const int bh = blockIdx.x >> 4;
  const int c  = blockIdx.x & 15;
  const unsigned short* src = vb + (size_t)bh*65536 + (size_t)c*64*64;
  {
    int r = tid >> 2, dh0 = (tid & 3) * 16;
    s16x8 a = *(const s16x8*)(src + r*64 + dh0);
    s16x8 b = *(const s16x8*)(src + r*64 + dh0 + 8);
    #pragma unroll
    for (int u = 0; u < 8; u++) t[r*65 + dh0 + u] = (unsigned short)a[u];
    #pragma unroll
    for (int u = 0; u < 8; u++) t[r*65 + dh0 + 8 + u] = (unsigned short)b[u];
  }
  __syncthreads();
  {
    int dh = tid >> 2, k16 = (tid & 3) * 16;
    union { s16x8 v[2]; unsigned short u[16]; } o;
    #pragma unroll
    for (int j = 0; j < 16; j++) o.u[j] = t[(k16 + j)*65 + dh];
    unsigned short* dst = vtb + (size_t)bh*65536 + (size_t)c*4096 + dh*64 + k16;
    *(s16x8*)dst       = o.v[0];
    *(s16x8*)(dst + 8) = o.v[1];
  }
}

// ---------------- Fused flash attention v5: LDS-table bias (no [H][N][N] plane) ----------------
// grid: 512 blocks = (b,h,qtile64), XCD-sibling mapping; 4 waves x 16 q-rows; 16 chunks of 64 keys.
__global__ __launch_bounds__(256, 2) void attn(
    const unsigned short* __restrict__ qb,
    const unsigned short* __restrict__ kb,
    const unsigned short* __restrict__ vtb,    // [bh][16][64 dh][64 kk]
    const unsigned short* __restrict__ tableb, // [8][4096] bf16, log2e-scaled
    unsigned short* __restrict__ yb,
    float* __restrict__ entp, float* __restrict__ maxp)
{
  __shared__ __align__(16) unsigned short lsK[2][4096];
  __shared__ __align__(16) unsigned short lsV[2][4096];
  __shared__ __align__(16) unsigned short lsT[4096];      // per-head relpos table (7.9KB used)
  __shared__ __align__(16) unsigned short lsP[4][1088];   // 16 rows x 68 shorts (136B)
  __shared__ float sE[4], sM[4];

  const int tid = threadIdx.x, lane = tid & 63, w = tid >> 6;
  const int i = lane & 15, g = lane >> 4;
  const int sw = (i & 7) << 4;

  const int blk = blockIdx.x;
  const int b   = (blk & 31) >> 3;
  const int grp = (blk >> 5) * 8 + (blk & 7);  // qt*8 + h
  const int h   = grp & 7;
  const int qt  = grp >> 3;
  const int q0  = qt * 64;
  const int bh  = b * 8 + h;

  const unsigned short* Qp = qb  + (size_t)bh * 65536;
  const unsigned short* Kp = kb  + (size_t)bh * 65536;
  const unsigned short* Vp = vtb + (size_t)bh * 65536;

  const int s0 = w*64 + lane, s1 = s0 + 256;
  const int r0 = s0 >> 3,     r1 = s1 >> 3;
  const int c0 = (((s0 & 7) * 16) ^ ((r0 & 7) << 4)) >> 1;
  const int c1 = (((s1 & 7) * 16) ^ ((r1 & 7) << 4)) >> 1;
  const unsigned short* pK0 = Kp + r0*64 + c0;
  const unsigned short* pK1 = Kp + r1*64 + c1;
  const unsigned short* pV0 = Vp + r0*64 + c0;
  const unsigned short* pV1 = Vp + r1*64 + c1;

  auto STAGE = [&](int bufi, int c){
    gl16(pK0 + c*4096, &lsK[bufi][0] + s0*8);
    gl16(pK1 + c*4096, &lsK[bufi][0] + s1*8);
    gl16(pV0 + c*4096, &lsV[bufi][0] + s0*8);
    gl16(pV1 + c*4096, &lsV[bufi][0] + s1*8);
  };

  // stage per-head table (8KB, once) then first chunk
  const unsigned short* pT = tableb + (h << 12);
  gl16(pT + tid*8,         &lsT[0] + tid*8);
  gl16(pT + (tid+256)*8,   &lsT[0] + (tid+256)*8);
  STAGE(0, 0);

  s16x8 qf0 = *(const s16x8*)(Qp + (size_t)(q0 + w*16 + i) * 64 + 8*g);
  s16x8 qf1 = *(const s16x8*)(Qp + (size_t)(q0 + w*16 + i) * 64 + 32 + 8*g);

  // analytic relpos base: n = q0 + w*16 + i ; lidx = (ch_n-ch_m+31)*63 + (cw_n-cw_m+31)
  const int n_  = q0 + w*16 + i;
  const int Abase0 = ((n_ >> 5) + 31)*63 + (n_ & 31) + 31 - 4*g;

  f32x4 O[4] = {};
  float m = -1e30f, l = 0.f, S1 = 0.f, emax = 0.f;

  char* Pbase = (char*)&lsP[w][0] + i*136;

  for (int c = 0; c < 16; ++c){
    __syncthreads();
    if (c < 15){
      STAGE((c + 1) & 1, c + 1);
      asm volatile("s_waitcnt vmcnt(4)" ::: "memory");
    } else {
      asm volatile("s_waitcnt vmcnt(0)" ::: "memory");
    }
    __syncthreads();

    const char* LK = (const char*)&lsK[c & 1][0];
    const char* LV = (const char*)&lsV[c & 1][0];
    const int ab = Abase0 - c*126;            // key row-pair advances 2 ch rows per chunk

    // ---- QK^T over 64 keys + LDS-gathered bias (log2 units) ----
    float sv[16];
    #pragma unroll
    for (int f = 0; f < 4; f++){
      s16x8 ka  = *(const s16x8*)(LK + (f*16 + i)*128 + ((16*g) ^ sw));
      s16x8 kb2 = *(const s16x8*)(LK + (f*16 + i)*128 + ((64 + 16*g) ^ sw));
      f32x4 sf = {};
      sf = MFMA16(ka,  qf0, sf, 0, 0, 0);
      sf = MFMA16(kb2, qf1, sf, 0, 0, 0);
      const int fb = ab - (f >> 1)*63 - (f & 1)*16;
      sv[4*f+0] = sf[0]*SCALE2 + bf2f(lsT[fb    ]);
      sv[4*f+1] = sf[1]*SCALE2 + bf2f(lsT[fb - 1]);
      sv[4*f+2] = sf[2]*SCALE2 + bf2f(lsT[fb - 2]);
      sv[4*f+3] = sf[3]*SCALE2 + bf2f(lsT[fb - 3]);
    }

    // ---- max tree + cross-g ----
    float t0 = fmaxf(fmaxf(sv[0],  sv[1]),  sv[2]);
    float t1 = fmaxf(fmaxf(sv[3],  sv[4]),  sv[5]);
    float t2 = fmaxf(fmaxf(sv[6],  sv[7]),  sv[8]);
    float t3 = fmaxf(fmaxf(sv[9],  sv[10]), sv[11]);
    float t4 = fmaxf(fmaxf(sv[12], sv[13]), sv[14]);
    float tmax = fmaxf(fmaxf(fmaxf(t0, t1), fmaxf(t2, t3)), fmaxf(t4, sv[15]));
    tmax = fmaxf(tmax, __shfl_xor(tmax, 16, 64));
    tmax = fmaxf(tmax, __shfl_xor(tmax, 32, 64));

    // ---- defer-max (THR=8 log2 units) ----
    if (!__all(tmax - m <= 8.0f)){
      float m_new = fmaxf(m, tmax);
      float alpha = exp2f(m - m_new);
      S1 = alpha * (S1 + (m - m_new) * l);
      l *= alpha;
      emax *= alpha;
      #pragma unroll
      for (int r = 0; r < 4; r++){
        float ar = __shfl(alpha, 4*g + r, 64);
        #pragma unroll
        for (int nf = 0; nf < 4; nf++) O[nf][r] *= ar;
      }
      m = m_new;
    }

    float e[16];
    float tl = 0.f, tS1 = 0.f;
    #pragma unroll
    for (int j = 0; j < 16; j++){
      float d = sv[j] - m;
      float ee = exp2f(d);
      e[j] = ee; tl += ee; tS1 += ee * d;
    }
    tl  += __shfl_xor(tl, 16, 64);  tl  += __shfl_xor(tl, 32, 64);
    tS1 += __shfl_xor(tS1, 16, 64); tS1 += __shfl_xor(tS1, 32, 64);
    S1 += tS1;
    l  += tl;
    emax = fmaxf(emax, exp2f(tmax - m));

    // ---- P transpose via per-wave LDS (truncating v_perm pack) ----
    #pragma unroll
    for (int f = 0; f < 4; f++){
      uint2 wp;
      wp.x = pk2t(e[4*f+0], e[4*f+1]);
      wp.y = pk2t(e[4*f+2], e[4*f+3]);
      *(uint2*)(Pbase + f*32 + 8*g) = wp;
    }
    asm volatile("s_waitcnt lgkmcnt(0)" ::: "memory");

    s16x8 pa0 = *(const s16x8*)(Pbase + 16*g);
    s16x8 pa1 = *(const s16x8*)(Pbase + 64 + 16*g);

    // ---- PV ----
    #pragma unroll
    for (int nf = 0; nf < 4; nf++){
      s16x8 v0 = *(const s16x8*)(LV + (nf*16 + i)*128 + ((16*g) ^ sw));
      s16x8 v1 = *(const s16x8*)(LV + (nf*16 + i)*128 + ((64 + 16*g) ^ sw));
      O[nf] = MFMA16(pa0, v0, O[nf], 0, 0, 0);
      O[nf] = MFMA16(pa1, v1, O[nf], 0, 0, 0);
    }
  }

  // ---- epilogue: normalize + write y ----
  float linv[4];
  #pragma unroll
  for (int r = 0; r < 4; r++){
    float lr = __shfl(l, 4*g + r, 64);
    linv[r] = 1.0f / lr;
  }
  #pragma unroll
  for (int nf = 0; nf < 4; nf++){
    #pragma unroll
    for (int r = 0; r < 4; r++){
      int row = q0 + w*16 + 4*g + r;
      int col = h*64 + nf*16 + i;
      yb[((size_t)(b << 10) + row) * 512 + col] = f2bf(O[nf][r] * linv[r]);
    }
  }

  // ---- stats: ent = ln(l) - ln2*S1/l ; pmax = emax/l ----
  float ent = __logf(l) - LN2 * S1 / l;
  float esum = (g == 0) ? ent : 0.f;
  float wmax = emax / l;
  #pragma unroll
  for (int off = 1; off < 64; off <<= 1){
    esum += __shfl_xor(esum, off, 64);
    wmax = fmaxf(wmax, __shfl_xor(wmax, off, 64));
  }
  if (lane == 0){ sE[w] = esum; sM[w] = wmax; }
  __syncthreads();
  if (tid == 0){
    entp[blk] = sE[0] + sE[1] + sE[2] + sE[3];
    maxp[blk] = fmaxf(fmaxf(sM[0], sM[1]), fmaxf(sM[2], sM[3]));
  }
}

// ---------------- GEMM2: out = y @ Wproj^T, 64x64 tile, grid 512 = 2/CU; block(0,0) finalizes ----------------
__global__ __launch_bounds__(256) void gemm_proj(
    const unsigned short* __restrict__ A,   // yb [4096][512]
    const unsigned short* __restrict__ Bt,  // wprojb [512][512]
    float* __restrict__ out,
    const float* __restrict__ entp, const float* __restrict__ maxp,
    float* __restrict__ scal)
{
  __shared__ __align__(16) unsigned short lA[64*32];
  __shared__ __align__(16) unsigned short lB[64*32];
  const int tid = threadIdx.x;
  const int lane = tid & 63;
  const int wid  = tid >> 6;
  const int i = lane & 15, g = lane >> 4;
  const int m0 = blockIdx.x * 64;
  const int n0 = blockIdx.y * 64;
  const int wr = wid >> 1, wc = wid & 1;   // wave tile 32 x 32
  const int K = 512;
  const int srA = tid >> 2;
  const int scc = (tid & 3) * 8;
  const unsigned short* ApS = A  + (size_t)(m0 + srA) * K + scc;
  const unsigned short* BpS = Bt + (size_t)(n0 + srA) * K + scc;
  unsigned short* lAs = lA + srA*32 + scc;
  unsigned short* lBs = lB + srA*32 + scc;

  f32x4 acc[2][2] = {};
  for (int k0 = 0; k0 < K; k0 += 32){
    gl16(ApS + k0, lAs);
    gl16(BpS + k0, lBs);
    __syncthreads();
    s16x8 aF[2], bF[2];
    #pragma unroll
    for (int mi = 0; mi < 2; mi++)
      aF[mi] = *(const s16x8*)(lA + (wr*32 + mi*16 + i)*32 + 8*g);
    #pragma unroll
    for (int ni = 0; ni < 2; ni++)
      bF[ni] = *(const s16x8*)(lB + (wc*32 + ni*16 + i)*32 + 8*g);
    #pragma unroll
    for (int mi = 0; mi < 2; mi++)
      #pragma unroll
      for (int ni = 0; ni < 2; ni++)
        acc[mi][ni] = MFMA16(aF[mi], bF[ni], acc[mi][ni], 0, 0, 0);
    __syncthreads();
  }
  #pragma unroll
  for (int mi = 0; mi < 2; mi++){
    #pragma unroll
    for (int r = 0; r < 4; r++){
      int row = m0 + wr*32 + mi*16 + 4*g + r;
      #pragma unroll
      for (int ni = 0; ni < 2; ni++){
        int col = n0 + wc*32 + ni*16 + i;
        out[(size_t)row * 512 + col] = acc[mi][ni][r];
      }
    }
  }

  // ---- fused finalize (stream-ordered after attn, so entp/maxp complete) ----
  if (blockIdx.x == 0 && blockIdx.y == 0 && tid < 64){
    float e = 0.f, mx = -1e30f;
    for (int j = tid; j < 512; j += 64){
      e += entp[j];
      mx = fmaxf(mx, maxp[j]);
    }
    #pragma unroll
    for (int off = 1; off < 64; off <<= 1){
      e += __shfl_xor(e, off, 64);
      mx = fmaxf(mx, __shfl_xor(mx, off, 64));
    }
    if (tid == 0){
      scal[0] = e / 32768.0f;    // mean entropy over B*H*N rows
      scal[1] = mx;              // amax
      scal[2] = 1.0f / 1024.0f;  // amean (rows sum to 1)
    }
  }
}

extern "C" void kernel_launch(void* const* d_in, const int* in_sizes, int n_in,
                              void* d_out, int out_size, void* d_ws, size_t ws_size,
                              hipStream_t stream){
  const float* x     = (const float*)d_in[0];
  const float* Wqkv  = (const float*)d_in[1];
  const float* Wproj = (const float*)d_in[2];
  const float* table = (const float*)d_in[3];
  const int*   index = (const int*)d_in[4];   // unused: relpos index is analytic
  (void)index;
  float* out = (float*)d_out;
  char* ws = (char*)d_ws;

  unsigned short* xb     = (unsigned short*)(ws + 0);          //  4 MB
  unsigned short* wqkvb  = (unsigned short*)(ws + 4194304);    //  1.5 MB
  unsigned short* wprojb = (unsigned short*)(ws + 5767168);    //  0.5 MB
  unsigned short* qb     = (unsigned short*)(ws + 6291456);    //  4 MB
  unsigned short* kb     = (unsigned short*)(ws + 10485760);   //  4 MB
  unsigned short* vtb    = (unsigned short*)(ws + 14680064);   //  4 MB
  unsigned short* yb     = (unsigned short*)(ws + 18874368);   //  4 MB
  unsigned short* tableb = (unsigned short*)(ws + 23068672);   // 64 KB [8][4096]
  float* entp            = (float*)(ws + 39845888);            //  2 KB
  float* maxp            = (float*)(ws + 39847936);            //  2 KB
  unsigned short* vb     = (unsigned short*)(ws + 41943040);   //  4 MB (natural-layout V)

  cvt_all<<<3088, 256, 0, stream>>>(x, Wqkv, Wproj, table, xb, wqkvb, wprojb, tableb);
  gemm_qkv<<<dim3(64, 12), 256, 0, stream>>>(xb, wqkvb, qb, kb, vb);
  v_transpose<<<512, 256, 0, stream>>>(vb, vtb);
  attn<<<512, 256, 0, stream>>>(qb, kb, vtb, tableb, yb, entp, maxp);
  gemm_proj<<<dim3(64, 8), 256, 0, stream>>>(yb, wprojb, out, entp, maxp, out + 2097152);
}

// Round 8
// 75.796 us; speedup vs baseline: 1.1917x; 1.0277x over previous
//
#include <hip/hip_runtime.h>

#define BB   4
#define NN   1024
#define DD   512
#define HH   8
#define DHH  64
#define SCALE2  0.180336880f     // 0.125 * log2(e)  -> scores in log2 units
#define LOG2E   1.44269504089f
#define LN2     0.69314718056f

typedef __attribute__((ext_vector_type(4))) float f32x4;
typedef __attribute__((ext_vector_type(8))) short s16x8;   // 8 bf16 (4 VGPRs)

#define MFMA16 __builtin_amdgcn_mfma_f32_16x16x32_bf16

__device__ __forceinline__ unsigned short f2bf(float f){
  union { float f; unsigned u; } v; v.f = f;
  unsigned r = v.u + 0x7FFFu + ((v.u >> 16) & 1u);   // RNE
  return (unsigned short)(r >> 16);
}
__device__ __forceinline__ float bf2f(unsigned short u){
  union { unsigned u; float f; } v; v.u = ((unsigned)u) << 16; return v.f;
}
// truncating bf16 pack of (a,b) -> one dword via v_perm (1 instr)
__device__ __forceinline__ unsigned pk2t(float a, float b){
  return __builtin_amdgcn_perm(__float_as_uint(b), __float_as_uint(a), 0x07060302u);
}
__device__ __forceinline__ void gl16(const void* g, void* l){
  __builtin_amdgcn_global_load_lds((const __attribute__((address_space(1))) unsigned int*)g,
                                   (__attribute__((address_space(3))) unsigned int*)l, 16, 0, 0);
}

// ------- fused fp32->bf16: x, Wqkv, Wproj, and relpos table (transposed, log2e-scaled) -------
__global__ void cvt_all(const float* __restrict__ x, const float* __restrict__ wq,
                        const float* __restrict__ wp, const float* __restrict__ table,
                        unsigned short* __restrict__ xb, unsigned short* __restrict__ wqb,
                        unsigned short* __restrict__ wpb, unsigned short* __restrict__ tableb){
  int idx = blockIdx.x * blockDim.x + threadIdx.x;
  if (idx < 786432){
    const float4* s; ushort4* d; int j;
    if (idx < 524288){ s = (const float4*)x;  d = (ushort4*)xb;  j = idx; }
    else if (idx < 720896){ s = (const float4*)wq; d = (ushort4*)wqb; j = idx - 524288; }
    else { s = (const float4*)wp; d = (ushort4*)wpb; j = idx - 720896; }
    float4 v = s[j];
    ushort4 o;
    o.x = f2bf(v.x); o.y = f2bf(v.y); o.z = f2bf(v.z); o.w = f2bf(v.w);
    d[j] = o;
  } else {
    int j = idx - 786432;            // 0..4095 ; table is [3969][8]
    float tv[8] = {0,0,0,0,0,0,0,0};
    if (j < 3969){
      const float4* t4 = (const float4*)table + (size_t)j * 2;
      float4 f0 = t4[0], f1 = t4[1];
      tv[0]=f0.x; tv[1]=f0.y; tv[2]=f0.z; tv[3]=f0.w;
      tv[4]=f1.x; tv[5]=f1.y; tv[6]=f1.z; tv[7]=f1.w;
    }
    #pragma unroll
    for (int h = 0; h < 8; h++)
      tableb[(h << 12) + j] = f2bf(tv[h] * LOG2E);
  }
}

// ---------------- GEMM1: qkv = x @ Wqkv^T, 64x128 tile, grid 768 = 3/CU ----------------
__global__ __launch_bounds__(256) void gemm_qkv(
    const unsigned short* __restrict__ A,    // xb [4096][512]
    const unsigned short* __restrict__ Bt,   // wqkvb [1536][512]
    unsigned short* __restrict__ qb, unsigned short* __restrict__ kb,
    unsigned short* __restrict__ vb)
{
  __shared__ __align__(16) unsigned short lA[64*32];
  __shared__ __align__(16) unsigned short lB[128*32];
  const int tid = threadIdx.x;
  const int lane = tid & 63;
  const int wid  = tid >> 6;
  const int i = lane & 15, g = lane >> 4;
  const int m0 = blockIdx.x * 64;
  const int n0 = blockIdx.y * 128;
  const int wr = wid >> 1, wc = wid & 1;   // wave tile 32 x 64
  const int K = 512;
  const int srA = tid >> 2;                // 0..63
  const int scc = (tid & 3) * 8;
  const unsigned short* ApS  = A  + (size_t)(m0 + srA) * K + scc;
  const unsigned short* BpS0 = Bt + (size_t)(n0 + srA) * K + scc;
  const unsigned short* BpS1 = Bt + (size_t)(n0 + 64 + srA) * K + scc;
  unsigned short* lAs  = lA + srA*32 + scc;
  unsigned short* lBs0 = lB + srA*32 + scc;
  unsigned short* lBs1 = lB + (64 + srA)*32 + scc;

  f32x4 acc[2][4] = {};
  for (int k0 = 0; k0 < K; k0 += 32){
    gl16(ApS + k0, lAs);
    gl16(BpS0 + k0, lBs0);
    gl16(BpS1 + k0, lBs1);
    __syncthreads();
    s16x8 aF[2], bF[4];
    #pragma unroll
    for (int mi = 0; mi < 2; mi++)
      aF[mi] = *(const s16x8*)(lA + (wr*32 + mi*16 + i)*32 + 8*g);
    #pragma unroll
    for (int ni = 0; ni < 4; ni++)
      bF[ni] = *(const s16x8*)(lB + (wc*64 + ni*16 + i)*32 + 8*g);
    #pragma unroll
    for (int mi = 0; mi < 2; mi++)
      #pragma unroll
      for (int ni = 0; ni < 4; ni++)
        acc[mi][ni] = MFMA16(aF[mi], bF[ni], acc[mi][ni], 0, 0, 0);
    __syncthreads();
  }
  #pragma unroll
  for (int mi = 0; mi < 2; mi++){
    #pragma unroll
    for (int r = 0; r < 4; r++){
      int row = m0 + wr*32 + mi*16 + 4*g + r;
      int b = row >> 10, tok = row & 1023;
      #pragma unroll
      for (int ni = 0; ni < 4; ni++){
        int col = n0 + wc*64 + ni*16 + i;
        unsigned short bv = f2bf(acc[mi][ni][r]);
        int part = col >> 9;
        int hh = (col >> 6) & 7;
        int dh = col & 63;
        int bh = b * 8 + hh;
        unsigned short* dst = (part == 0) ? qb : (part == 1) ? kb : vb;
        dst[((size_t)(bh << 10) + tok) * 64 + dh] = bv;
      }
    }
  }
}

// ---------------- V transpose: vb[bh][tok][dh] -> vtb[bh][chunk][dh 64][kk 64] ----------------
__global__ __launch_bounds__(256) void v_transpose(
    const unsigned short* __restrict__ vb,
    unsigned short* __restrict__ vtb)
{
  __shared__ unsigned short t[64*65 + 8];
  const int tid = threadIdx.x;
  const int bh = blockIdx.x >> 4;
  const int c  = blockIdx.x & 15;
  const unsigned short* src = vb + (size_t)bh*65536 + (size_t)c*64*64;
  {
    int r = tid >> 2, dh0 = (tid & 3) * 16;
    s16x8 a = *(const s16x8*)(src + r*64 + dh0);
    s16x8 b = *(const s16x8*)(src + r*64 + dh0 + 8);
    #pragma unroll
    for (int u = 0; u < 8; u++) t[r*65 + dh0 + u] = (unsigned short)a[u];
    #pragma unroll
    for (int u = 0; u < 8; u++) t[r*65 + dh0 + 8 + u] = (unsigned short)b[u];
  }
  __syncthreads();
  {
    int dh = tid >> 2, k16 = (tid & 3) * 16;
    union { s16x8 v[2]; unsigned short u[16]; } o;
    #pragma unroll
    for (int j = 0; j < 16; j++) o.u[j] = t[(k16 + j)*65 + dh];
    unsigned short* dst = vtb + (size_t)bh*65536 + (size_t)c*4096 + dh*64 + k16;
    *(s16x8*)dst       = o.v[0];
    *(s16x8*)(dst + 8) = o.v[1];
  }
}

// ---- Fused flash attention v6: shuffle-free common path (deferred l/S1/emax partials) ----
// grid: 512 blocks = (b,h,qtile64), XCD-sibling mapping; 4 waves x 16 q-rows; 16 chunks of 64 keys.
__global__ __launch_bounds__(256, 2) void attn(
    const unsigned short* __restrict__ qb,
    const unsigned short* __restrict__ kb,
    const unsigned short* __restrict__ vtb,    // [bh][16][64 dh][64 kk]
    const unsigned short* __restrict__ tableb, // [8][4096] bf16, log2e-scaled
    unsigned short* __restrict__ yb,
    float* __restrict__ entp, float* __restrict__ maxp)
{
  __shared__ __align__(16) unsigned short lsK[2][4096];
  __shared__ __align__(16) unsigned short lsV[2][4096];
  __shared__ __align__(16) unsigned short lsT[4096];      // per-head relpos table (7.9KB used)
  __shared__ __align__(16) unsigned short lsP[4][1088];   // 16 rows x 68 shorts (136B)
  __shared__ float sE[4], sM[4];

  const int tid = threadIdx.x, lane = tid & 63, w = tid >> 6;
  const int i = lane & 15, g = lane >> 4;
  const int sw = (i & 7) << 4;

  const int blk = blockIdx.x;
  const int b   = (blk & 31) >> 3;
  const int grp = (blk >> 5) * 8 + (blk & 7);  // qt*8 + h
  const int h   = grp & 7;
  const int qt  = grp >> 3;
  const int q0  = qt * 64;
  const int bh  = b * 8 + h;

  const unsigned short* Qp = qb  + (size_t)bh * 65536;
  const unsigned short* Kp = kb  + (size_t)bh * 65536;
  const unsigned short* Vp = vtb + (size_t)bh * 65536;

  // Q fragments FIRST (oldest in vmcnt FIFO; compiler wait for them won't drain prefetch)
  s16x8 qf0 = *(const s16x8*)(Qp + (size_t)(q0 + w*16 + i) * 64 + 8*g);
  s16x8 qf1 = *(const s16x8*)(Qp + (size_t)(q0 + w*16 + i) * 64 + 32 + 8*g);

  const int s0 = w*64 + lane, s1 = s0 + 256;
  const int r0 = s0 >> 3,     r1 = s1 >> 3;
  const int c0 = (((s0 & 7) * 16) ^ ((r0 & 7) << 4)) >> 1;
  const int c1 = (((s1 & 7) * 16) ^ ((r1 & 7) << 4)) >> 1;
  const unsigned short* pK0 = Kp + r0*64 + c0;
  const unsigned short* pK1 = Kp + r1*64 + c1;
  const unsigned short* pV0 = Vp + r0*64 + c0;
  const unsigned short* pV1 = Vp + r1*64 + c1;

  auto STAGE = [&](int bufi, int c){
    gl16(pK0 + c*4096, &lsK[bufi][0] + s0*8);
    gl16(pK1 + c*4096, &lsK[bufi][0] + s1*8);
    gl16(pV0 + c*4096, &lsV[bufi][0] + s0*8);
    gl16(pV1 + c*4096, &lsV[bufi][0] + s1*8);
  };

  // stage per-head table (8KB, once) then first chunk
  const unsigned short* pT = tableb + (h << 12);
  gl16(pT + tid*8,         &lsT[0] + tid*8);
  gl16(pT + (tid+256)*8,   &lsT[0] + (tid+256)*8);
  STAGE(0, 0);

  // analytic relpos base: n = q0 + w*16 + i ; lidx = (ch_n-ch_m+31)*63 + (cw_n-cw_m+31)
  const int n_  = q0 + w*16 + i;
  const int Abase0 = ((n_ >> 5) + 31)*63 + (n_ & 31) + 31 - 4*g;

  f32x4 O[4] = {};
  // per-LANE partials (deferred reduction): l,S1,emax cover only this lane's 16 keys/chunk
  float m = -1e30f, l = 0.f, S1 = 0.f, emax = 0.f;

  char* Pbase = (char*)&lsP[w][0] + i*136;

  for (int c = 0; c < 16; ++c){
    __syncthreads();
    if (c < 15){
      STAGE((c + 1) & 1, c + 1);
      asm volatile("s_waitcnt vmcnt(4)" ::: "memory");
    } else {
      asm volatile("s_waitcnt vmcnt(0)" ::: "memory");
    }
    __syncthreads();

    const char* LK = (const char*)&lsK[c & 1][0];
    const char* LV = (const char*)&lsV[c & 1][0];
    const int ab = Abase0 - c*126;

    // ---- QK^T over 64 keys + LDS-gathered bias (log2 units) ----
    float sv[16];
    #pragma unroll
    for (int f = 0; f < 4; f++){
      s16x8 ka  = *(const s16x8*)(LK + (f*16 + i)*128 + ((16*g) ^ sw));
      s16x8 kb2 = *(const s16x8*)(LK + (f*16 + i)*128 + ((64 + 16*g) ^ sw));
      f32x4 sf = {};
      sf = MFMA16(ka,  qf0, sf, 0, 0, 0);
      sf = MFMA16(kb2, qf1, sf, 0, 0, 0);
      const int fb = ab - (f >> 1)*63 - (f & 1)*16;
      sv[4*f+0] = sf[0]*SCALE2 + bf2f(lsT[fb    ]);
      sv[4*f+1] = sf[1]*SCALE2 + bf2f(lsT[fb - 1]);
      sv[4*f+2] = sf[2]*SCALE2 + bf2f(lsT[fb - 2]);
      sv[4*f+3] = sf[3]*SCALE2 + bf2f(lsT[fb - 3]);
    }

    // ---- lane-local max tree only (no cross-lane in common path) ----
    float t0 = fmaxf(fmaxf(sv[0],  sv[1]),  sv[2]);
    float t1 = fmaxf(fmaxf(sv[3],  sv[4]),  sv[5]);
    float t2 = fmaxf(fmaxf(sv[6],  sv[7]),  sv[8]);
    float t3 = fmaxf(fmaxf(sv[9],  sv[10]), sv[11]);
    float t4 = fmaxf(fmaxf(sv[12], sv[13]), sv[14]);
    float ltmax = fmaxf(fmaxf(fmaxf(t0, t1), fmaxf(t2, t3)), fmaxf(t4, sv[15]));

    // ---- defer-max vote; rare branch does the cross-g max + rescale ----
    if (!__all(ltmax - m <= 8.0f)){
      float rmax = fmaxf(ltmax, __shfl_xor(ltmax, 16, 64));
      rmax = fmaxf(rmax, __shfl_xor(rmax, 32, 64));
      float m_new = fmaxf(m, rmax);
      float alpha = exp2f(m - m_new);
      S1 = alpha * (S1 + (m - m_new) * l);
      l *= alpha;
      emax *= alpha;
      #pragma unroll
      for (int r = 0; r < 4; r++){
        float ar = __shfl(alpha, 4*g + r, 64);
        #pragma unroll
        for (int nf = 0; nf < 4; nf++) O[nf][r] *= ar;
      }
      m = m_new;
    }

    // ---- exp + per-lane partial accumulation (no shuffles) ----
    float e[16];
    float tl = 0.f, tS1 = 0.f;
    #pragma unroll
    for (int j = 0; j < 16; j++){
      float d = sv[j] - m;
      float ee = exp2f(d);
      e[j] = ee; tl += ee; tS1 += ee * d;
    }
    l  += tl;
    S1 += tS1;
    emax = fmaxf(emax, exp2f(ltmax - m));

    // ---- P transpose via per-wave LDS (truncating v_perm pack) ----
    #pragma unroll
    for (int f = 0; f < 4; f++){
      uint2 wp;
      wp.x = pk2t(e[4*f+0], e[4*f+1]);
      wp.y = pk2t(e[4*f+2], e[4*f+3]);
      *(uint2*)(Pbase + f*32 + 8*g) = wp;
    }
    asm volatile("s_waitcnt lgkmcnt(0)" ::: "memory");

    s16x8 pa0 = *(const s16x8*)(Pbase + 16*g);
    s16x8 pa1 = *(const s16x8*)(Pbase + 64 + 16*g);

    // ---- PV ----
    #pragma unroll
    for (int nf = 0; nf < 4; nf++){
      s16x8 v0 = *(const s16x8*)(LV + (nf*16 + i)*128 + ((16*g) ^ sw));
      s16x8 v1 = *(const s16x8*)(LV + (nf*16 + i)*128 + ((64 + 16*g) ^ sw));
      O[nf] = MFMA16(pa0, v0, O[nf], 0, 0, 0);
      O[nf] = MFMA16(pa1, v1, O[nf], 0, 0, 0);
    }
  }

  // ---- epilogue: reduce per-lane partials across g (once), normalize, write y ----
  float l2 = l + __shfl_xor(l, 16, 64);
  float lrow = l2 + __shfl_xor(l2, 32, 64);
  float s2 = S1 + __shfl_xor(S1, 16, 64);
  float S1row = s2 + __shfl_xor(s2, 32, 64);

  float linv[4];
  #pragma unroll
  for (int r = 0; r < 4; r++){
    float lr = __shfl(lrow, 4*g + r, 64);
    linv[r] = 1.0f / lr;
  }
  #pragma unroll
  for (int nf = 0; nf < 4; nf++){
    #pragma unroll
    for (int r = 0; r < 4; r++){
      int row = q0 + w*16 + 4*g + r;
      int col = h*64 + nf*16 + i;
      yb[((size_t)(b << 10) + row) * 512 + col] = f2bf(O[nf][r] * linv[r]);
    }
  }

  // ---- stats: ent = ln(lrow) - ln2*S1row/lrow ; pmax = max(emax)/lrow ----
  float ent = __logf(lrow) - LN2 * S1row / lrow;
  float esum = (g == 0) ? ent : 0.f;
  float wmax = emax / lrow;     // partial; full max taken by 64-lane reduce below
  #pragma unroll
  for (int off = 1; off < 64; off <<= 1){
    esum += __shfl_xor(esum, off, 64);
    wmax = fmaxf(wmax, __shfl_xor(wmax, off, 64));
  }
  if (lane == 0){ sE[w] = esum; sM[w] = wmax; }
  __syncthreads();
  if (tid == 0){
    entp[blk] = sE[0] + sE[1] + sE[2] + sE[3];
    maxp[blk] = fmaxf(fmaxf(sM[0], sM[1]), fmaxf(sM[2], sM[3]));
  }
}

// ---------------- GEMM2: out = y @ Wproj^T, 64x64 tile, grid 512 = 2/CU; block(0,0) finalizes ----------------
__global__ __launch_bounds__(256) void gemm_proj(
    const unsigned short* __restrict__ A,   // yb [4096][512]
    const unsigned short* __restrict__ Bt,  // wprojb [512][512]
    float* __restrict__ out,
    const float* __restrict__ entp, const float* __restrict__ maxp,
    float* __restrict__ scal)
{
  __shared__ __align__(16) unsigned short lA[64*32];
  __shared__ __align__(16) unsigned short lB[64*32];
  const int tid = threadIdx.x;
  const int lane = tid & 63;
  const int wid  = tid >> 6;
  const int i = lane & 15, g = lane >> 4;
  const int m0 = blockIdx.x * 64;
  const int n0 = blockIdx.y * 64;
  const int wr = wid >> 1, wc = wid & 1;   // wave tile 32 x 32
  const int K = 512;
  const int srA = tid >> 2;
  const int scc = (tid & 3) * 8;
  const unsigned short* ApS = A  + (size_t)(m0 + srA) * K + scc;
  const unsigned short* BpS = Bt + (size_t)(n0 + srA) * K + scc;
  unsigned short* lAs = lA + srA*32 + scc;
  unsigned short* lBs = lB + srA*32 + scc;

  f32x4 acc[2][2] = {};
  for (int k0 = 0; k0 < K; k0 += 32){
    gl16(ApS + k0, lAs);
    gl16(BpS + k0, lBs);
    __syncthreads();
    s16x8 aF[2], bF[2];
    #pragma unroll
    for (int mi = 0; mi < 2; mi++)
      aF[mi] = *(const s16x8*)(lA + (wr*32 + mi*16 + i)*32 + 8*g);
    #pragma unroll
    for (int ni = 0; ni < 2; ni++)
      bF[ni] = *(const s16x8*)(lB + (wc*32 + ni*16 + i)*32 + 8*g);
    #pragma unroll
    for (int mi = 0; mi < 2; mi++)
      #pragma unroll
      for (int ni = 0; ni < 2; ni++)
        acc[mi][ni] = MFMA16(aF[mi], bF[ni], acc[mi][ni], 0, 0, 0);
    __syncthreads();
  }
  #pragma unroll
  for (int mi = 0; mi < 2; mi++){
    #pragma unroll
    for (int r = 0; r < 4; r++){
      int row = m0 + wr*32 + mi*16 + 4*g + r;
      #pragma unroll
      for (int ni = 0; ni < 2; ni++){
        int col = n0 + wc*32 + ni*16 + i;
        out[(size_t)row * 512 + col] = acc[mi][ni][r];
      }
    }
  }

  // ---- fused finalize (stream-ordered after attn, so entp/maxp complete) ----
  if (blockIdx.x == 0 && blockIdx.y == 0 && tid < 64){
    float e = 0.f, mx = -1e30f;
    for (int j = tid; j < 512; j += 64){
      e += entp[j];
      mx = fmaxf(mx, maxp[j]);
    }
    #pragma unroll
    for (int off = 1; off < 64; off <<= 1){
      e += __shfl_xor(e, off, 64);
      mx = fmaxf(mx, __shfl_xor(mx, off, 64));
    }
    if (tid == 0){
      scal[0] = e / 32768.0f;    // mean entropy over B*H*N rows
      scal[1] = mx;              // amax
      scal[2] = 1.0f / 1024.0f;  // amean (rows sum to 1)
    }
  }
}

extern "C" void kernel_launch(void* const* d_in, const int* in_sizes, int n_in,
                              void* d_out, int out_size, void* d_ws, size_t ws_size,
                              hipStream_t stream){
  const float* x     = (const float*)d_in[0];
  const float* Wqkv  = (const float*)d_in[1];
  const float* Wproj = (const float*)d_in[2];
  const float* table = (const float*)d_in[3];
  const int*   index = (const int*)d_in[4];   // unused: relpos index is analytic
  (void)index;
  float* out = (float*)d_out;
  char* ws = (char*)d_ws;

  unsigned short* xb     = (unsigned short*)(ws + 0);          //  4 MB
  unsigned short* wqkvb  = (unsigned short*)(ws + 4194304);    //  1.5 MB
  unsigned short* wprojb = (unsigned short*)(ws + 5767168);    //  0.5 MB
  unsigned short* qb     = (unsigned short*)(ws + 6291456);    //  4 MB
  unsigned short* kb     = (unsigned short*)(ws + 10485760);   //  4 MB
  unsigned short* vtb    = (unsigned short*)(ws + 14680064);   //  4 MB
  unsigned short* yb     = (unsigned short*)(ws + 18874368);   //  4 MB
  unsigned short* tableb = (unsigned short*)(ws + 23068672);   // 64 KB [8][4096]
  float* entp            = (float*)(ws + 39845888);            //  2 KB
  float* maxp            = (float*)(ws + 39847936);            //  2 KB
  unsigned short* vb     = (unsigned short*)(ws + 41943040);   //  4 MB (natural-layout V)

  cvt_all<<<3088, 256, 0, stream>>>(x, Wqkv, Wproj, table, xb, wqkvb, wprojb, tableb);
  gemm_qkv<<<dim3(64, 12), 256, 0, stream>>>(xb, wqkvb, qb, kb, vb);
  v_transpose<<<512, 256, 0, stream>>>(vb, vtb);
  attn<<<512, 256, 0, stream>>>(qb, kb, vtb, tableb, yb, entp, maxp);
  gemm_proj<<<dim3(64, 8), 256, 0, stream>>>(yb, wprojb, out, entp, maxp, out + 2097152);
}

// Round 9
// 71.026 us; speedup vs baseline: 1.2717x; 1.0672x over previous
//
#include <hip/hip_runtime.h>

#define SCALE2  0.180336880f     // 0.125 * log2(e)  -> scores in log2 units
#define LOG2E   1.44269504089f
#define LN2     0.69314718056f

typedef __attribute__((ext_vector_type(4))) float f32x4;
typedef __attribute__((ext_vector_type(8))) short s16x8;   // 8 bf16 (4 VGPRs)

#define MFMA16 __builtin_amdgcn_mfma_f32_16x16x32_bf16

__device__ __forceinline__ unsigned short f2bf(float f){
  union { float f; unsigned u; } v; v.f = f;
  unsigned r = v.u + 0x7FFFu + ((v.u >> 16) & 1u);   // RNE
  return (unsigned short)(r >> 16);
}
__device__ __forceinline__ float bf2f(unsigned short u){
  union { unsigned u; float f; } v; v.u = ((unsigned)u) << 16; return v.f;
}
// truncating bf16 pack of (a,b) -> one dword via v_perm (1 instr)
__device__ __forceinline__ unsigned pk2t(float a, float b){
  return __builtin_amdgcn_perm(__float_as_uint(b), __float_as_uint(a), 0x07060302u);
}
__device__ __forceinline__ void gl16(const void* g, void* l){
  __builtin_amdgcn_global_load_lds((const __attribute__((address_space(1))) unsigned int*)g,
                                   (__attribute__((address_space(3))) unsigned int*)l, 16, 0, 0);
}

// ------- fused fp32->bf16: x, Wqkv, Wproj, and relpos table (transposed, log2e-scaled) -------
__global__ void cvt_all(const float* __restrict__ x, const float* __restrict__ wq,
                        const float* __restrict__ wp, const float* __restrict__ table,
                        unsigned short* __restrict__ xb, unsigned short* __restrict__ wqb,
                        unsigned short* __restrict__ wpb, unsigned short* __restrict__ tableb){
  int idx = blockIdx.x * blockDim.x + threadIdx.x;
  if (idx < 786432){
    const float4* s; ushort4* d; int j;
    if (idx < 524288){ s = (const float4*)x;  d = (ushort4*)xb;  j = idx; }
    else if (idx < 720896){ s = (const float4*)wq; d = (ushort4*)wqb; j = idx - 524288; }
    else { s = (const float4*)wp; d = (ushort4*)wpb; j = idx - 720896; }
    float4 v = s[j];
    ushort4 o;
    o.x = f2bf(v.x); o.y = f2bf(v.y); o.z = f2bf(v.z); o.w = f2bf(v.w);
    d[j] = o;
  } else {
    int j = idx - 786432;            // 0..4095 ; table is [3969][8]
    float tv[8] = {0,0,0,0,0,0,0,0};
    if (j < 3969){
      const float4* t4 = (const float4*)table + (size_t)j * 2;
      float4 f0 = t4[0], f1 = t4[1];
      tv[0]=f0.x; tv[1]=f0.y; tv[2]=f0.z; tv[3]=f0.w;
      tv[4]=f1.x; tv[5]=f1.y; tv[6]=f1.z; tv[7]=f1.w;
    }
    #pragma unroll
    for (int h = 0; h < 8; h++)
      tableb[(h << 12) + j] = f2bf(tv[h] * LOG2E);
  }
}

// ---------------- GEMM1: qkv = x @ Wqkv^T, 64x128 tile, grid 768 = 3/CU ----------------
__global__ __launch_bounds__(256) void gemm_qkv(
    const unsigned short* __restrict__ A,    // xb [4096][512]
    const unsigned short* __restrict__ Bt,   // wqkvb [1536][512]
    unsigned short* __restrict__ qb, unsigned short* __restrict__ kb,
    unsigned short* __restrict__ vb)
{
  __shared__ __align__(16) unsigned short lA[64*32];
  __shared__ __align__(16) unsigned short lB[128*32];
  const int tid = threadIdx.x;
  const int lane = tid & 63;
  const int wid  = tid >> 6;
  const int i = lane & 15, g = lane >> 4;
  const int m0 = blockIdx.x * 64;
  const int n0 = blockIdx.y * 128;
  const int wr = wid >> 1, wc = wid & 1;   // wave tile 32 x 64
  const int K = 512;
  const int srA = tid >> 2;                // 0..63
  const int scc = (tid & 3) * 8;
  const unsigned short* ApS  = A  + (size_t)(m0 + srA) * K + scc;
  const unsigned short* BpS0 = Bt + (size_t)(n0 + srA) * K + scc;
  const unsigned short* BpS1 = Bt + (size_t)(n0 + 64 + srA) * K + scc;
  unsigned short* lAs  = lA + srA*32 + scc;
  unsigned short* lBs0 = lB + srA*32 + scc;
  unsigned short* lBs1 = lB + (64 + srA)*32 + scc;

  f32x4 acc[2][4] = {};
  for (int k0 = 0; k0 < K; k0 += 32){
    gl16(ApS + k0, lAs);
    gl16(BpS0 + k0, lBs0);
    gl16(BpS1 + k0, lBs1);
    __syncthreads();
    s16x8 aF[2], bF[4];
    #pragma unroll
    for (int mi = 0; mi < 2; mi++)
      aF[mi] = *(const s16x8*)(lA + (wr*32 + mi*16 + i)*32 + 8*g);
    #pragma unroll
    for (int ni = 0; ni < 4; ni++)
      bF[ni] = *(const s16x8*)(lB + (wc*64 + ni*16 + i)*32 + 8*g);
    #pragma unroll
    for (int mi = 0; mi < 2; mi++)
      #pragma unroll
      for (int ni = 0; ni < 4; ni++)
        acc[mi][ni] = MFMA16(aF[mi], bF[ni], acc[mi][ni], 0, 0, 0);
    __syncthreads();
  }
  #pragma unroll
  for (int mi = 0; mi < 2; mi++){
    #pragma unroll
    for (int r = 0; r < 4; r++){
      int row = m0 + wr*32 + mi*16 + 4*g + r;
      int b = row >> 10, tok = row & 1023;
      #pragma unroll
      for (int ni = 0; ni < 4; ni++){
        int col = n0 + wc*64 + ni*16 + i;
        unsigned short bv = f2bf(acc[mi][ni][r]);
        int part = col >> 9;
        int hh = (col >> 6) & 7;
        int dh = col & 63;
        int bh = b * 8 + hh;
        unsigned short* dst = (part == 0) ? qb : (part == 1) ? kb : vb;
        dst[((size_t)(bh << 10) + tok) * 64 + dh] = bv;
      }
    }
  }
}

// -------- V transpose: vb[bh][tok][dh] -> vt2[bh][cc 32][j=d>>1 32][d&1][k 32] --------
// 32-key chunk tiles with paired-d 128B rows (matches attn K-tile staging geometry).
__global__ __launch_bounds__(256) void v_transpose(
    const unsigned short* __restrict__ vb,
    unsigned short* __restrict__ vt2)
{
  __shared__ unsigned short t[64*65 + 8];
  const int tid = threadIdx.x;
  const int bh = blockIdx.x >> 4;
  const int c  = blockIdx.x & 15;            // 64-key block
  const unsigned short* src = vb + (size_t)bh*65536 + (size_t)c*64*64;
  {
    int r = tid >> 2, dh0 = (tid & 3) * 16;
    s16x8 a = *(const s16x8*)(src + r*64 + dh0);
    s16x8 b = *(const s16x8*)(src + r*64 + dh0 + 8);
    #pragma unroll
    for (int u = 0; u < 8; u++) t[r*65 + dh0 + u] = (unsigned short)a[u];
    #pragma unroll
    for (int u = 0; u < 8; u++) t[r*65 + dh0 + 8 + u] = (unsigned short)b[u];
  }
  __syncthreads();
  {
    int dh = tid >> 2, k16 = (tid & 3) * 16;   // 16 keys starting at c*64+k16
    union { s16x8 v[2]; unsigned short u[16]; } o;
    #pragma unroll
    for (int j = 0; j < 16; j++) o.u[j] = t[(k16 + j)*65 + dh];
    int cc  = c*2 + (k16 >> 5);
    int kk0 = k16 & 31;
    int jr  = dh >> 1, dl = dh & 1;
    unsigned short* dst = vt2 + (size_t)bh*65536 + ((size_t)cc*32 + jr)*64 + dl*32 + kk0;
    *(s16x8*)dst       = o.v[0];
    *(s16x8*)(dst + 8) = o.v[1];
  }
}

// ---- Fused flash attention v7: 1024 blocks, in-block KV split x2, 32-key chunks ----
// block = (b,h,qtile32); waves: (w&1)=q sub-tile 16, (w>>1)=kv half 512. 16 chunks/half.
#define SM_KOFF 0
#define SM_VOFF 16384
#define SM_POFF 32768
#define SM_SIZE (32768 + 4608)
__global__ __launch_bounds__(256, 4) void attn(
    const unsigned short* __restrict__ qb,
    const unsigned short* __restrict__ kb,
    const unsigned short* __restrict__ vt2,    // [bh][32cc][32j][2dl][32k]
    const unsigned short* __restrict__ tableb, // [8][4096] bf16, log2e-scaled
    unsigned short* __restrict__ yb,
    float* __restrict__ entp, float* __restrict__ maxp)
{
  __shared__ __align__(16) char smem[SM_SIZE];
  __shared__ float sE[2], sMx[2];

  const int tid = threadIdx.x, lane = tid & 63, w = tid >> 6;
  const int i = lane & 15, g = lane >> 4;

  const int blk = blockIdx.x;
  const int bh  = blk >> 5;
  const int qt  = blk & 31;
  const int q0  = qt * 32;
  const int b   = bh >> 3;
  const int h   = bh & 7;

  const int qs = w & 1;        // q sub-tile
  const int s  = w >> 1;       // kv half

  const unsigned short* Qp = qb  + (size_t)bh * 65536;
  const unsigned short* Kp = kb  + (size_t)bh * 65536;
  const unsigned short* Vp = vt2 + (size_t)bh * 65536 + (size_t)s * 32768;  // half base
  const unsigned short* tb = tableb + (h << 12);

  // Q fragments: q-row n = q0 + qs*16 + i
  const int n_ = q0 + qs*16 + i;
  s16x8 qf0 = *(const s16x8*)(Qp + (size_t)n_ * 64 + 8*g);
  s16x8 qf1 = *(const s16x8*)(Qp + (size_t)n_ * 64 + 32 + 8*g);

  // staging geometry (identical for K and V tiles: 32 rows x 128B, XOR-swizzled)
  const int slot = qs*64 + lane;                 // [0,128) within half
  const int rA0 = slot >> 3, rA1 = rA0 + 16;
  const int cb0 = ((slot & 7)*16) ^ ((rA0 & 7) << 4);
  const int cb1 = ((slot & 7)*16) ^ ((rA1 & 7) << 4);
  const unsigned short* pK0 = Kp + (s*512 + rA0)*64 + (cb0 >> 1);
  const unsigned short* pK1 = Kp + (s*512 + rA1)*64 + (cb1 >> 1);
  const unsigned short* pV0 = Vp + rA0*64 + (cb0 >> 1);
  const unsigned short* pV1 = Vp + rA1*64 + (cb1 >> 1);

  auto STAGE = [&](int buf, int cc){
    char* Kd = smem + SM_KOFF + (s*2 + buf)*4096;
    char* Vd = smem + SM_VOFF + (s*2 + buf)*4096;
    gl16(pK0 + cc*2048, Kd + slot*16);
    gl16(pK1 + cc*2048, Kd + slot*16 + 2048);
    gl16(pV0 + cc*2048, Vd + slot*16);
    gl16(pV1 + cc*2048, Vd + slot*16 + 2048);
  };

  // analytic relpos: ch_k for chunk cc = s*16 + cc
  const int A0 = ((n_ >> 5) - s*16 + 31)*63 + (n_ & 31) + 31 - 4*g;

  f32x4 O[4] = {};
  float m = -1e30f, l = 0.f, S1 = 0.f, emax = 0.f;   // per-lane partials

  char* Pbase = smem + SM_POFF + w*1152 + i*72;

  STAGE(0, 0);
  for (int cc = 0; cc < 16; ++cc){
    __syncthreads();
    if (cc < 15){
      STAGE((cc + 1) & 1, cc + 1);
      asm volatile("s_waitcnt vmcnt(4)" ::: "memory");
    } else {
      asm volatile("s_waitcnt vmcnt(0)" ::: "memory");
    }
    __syncthreads();

    const char* LK = smem + SM_KOFF + (s*2 + (cc & 1))*4096;
    const char* LV = smem + SM_VOFF + (s*2 + (cc & 1))*4096;
    const int ab = A0 - 63*cc;

    // ---- QK^T over 32 keys + analytic bias from global table (L1-hot) ----
    float sv[8];
    #pragma unroll
    for (int f = 0; f < 2; f++){
      const int kr = f*16 + i;
      s16x8 ka  = *(const s16x8*)(LK + kr*128 + ((16*g)      ^ ((kr & 7) << 4)));
      s16x8 kb2 = *(const s16x8*)(LK + kr*128 + ((64 + 16*g) ^ ((kr & 7) << 4)));
      f32x4 sf = {};
      sf = MFMA16(ka,  qf0, sf, 0, 0, 0);
      sf = MFMA16(kb2, qf1, sf, 0, 0, 0);
      const int fb = ab - 16*f;
      sv[4*f+0] = sf[0]*SCALE2 + bf2f(tb[fb    ]);
      sv[4*f+1] = sf[1]*SCALE2 + bf2f(tb[fb - 1]);
      sv[4*f+2] = sf[2]*SCALE2 + bf2f(tb[fb - 2]);
      sv[4*f+3] = sf[3]*SCALE2 + bf2f(tb[fb - 3]);
    }

    // ---- lane-local max (8) + defer-max vote ----
    float t0 = fmaxf(fmaxf(sv[0], sv[1]), fmaxf(sv[2], sv[3]));
    float t1 = fmaxf(fmaxf(sv[4], sv[5]), fmaxf(sv[6], sv[7]));
    float ltmax = fmaxf(t0, t1);

    if (!__all(ltmax - m <= 8.0f)){
      float rmax = fmaxf(ltmax, __shfl_xor(ltmax, 16, 64));
      rmax = fmaxf(rmax, __shfl_xor(rmax, 32, 64));
      float m_new = fmaxf(m, rmax);
      float alpha = exp2f(m - m_new);
      S1 = alpha * (S1 + (m - m_new) * l);
      l *= alpha;
      emax *= alpha;
      #pragma unroll
      for (int r = 0; r < 4; r++){
        float ar = __shfl(alpha, 4*g + r, 64);
        #pragma unroll
        for (int nf = 0; nf < 4; nf++) O[nf][r] *= ar;
      }
      m = m_new;
    }

    // ---- exp + per-lane partials (no cross-lane) ----
    float e[8];
    float tl = 0.f, tS1 = 0.f;
    #pragma unroll
    for (int j = 0; j < 8; j++){
      float d = sv[j] - m;
      float ee = exp2f(d);
      e[j] = ee; tl += ee; tS1 += ee * d;
    }
    l  += tl;
    S1 += tS1;
    emax = fmaxf(emax, exp2f(ltmax - m));

    // ---- P transpose via tiny per-wave LDS ----
    #pragma unroll
    for (int f = 0; f < 2; f++){
      uint2 wp;
      wp.x = pk2t(e[4*f+0], e[4*f+1]);
      wp.y = pk2t(e[4*f+2], e[4*f+3]);
      *(uint2*)(Pbase + 32*f + 8*g) = wp;
    }
    asm volatile("s_waitcnt lgkmcnt(0)" ::: "memory");
    s16x8 pa = *(const s16x8*)(Pbase + 16*g);   // keys 8g..8g+7

    // ---- PV: paired-d rows, swizzled ----
    #pragma unroll
    for (int nf = 0; nf < 4; nf++){
      const int jr = nf*8 + (i >> 1);
      s16x8 vf = *(const s16x8*)(LV + jr*128 + (((i & 1)*64 + 16*g) ^ ((jr & 7) << 4)));
      O[nf] = MFMA16(pa, vf, O[nf], 0, 0, 0);
    }
  }

  // ---- reduce per-lane partials across g (row values) ----
  float l2 = l + __shfl_xor(l, 16, 64);
  float lrow = l2 + __shfl_xor(l2, 32, 64);
  float s2 = S1 + __shfl_xor(S1, 16, 64);
  float S1row = s2 + __shfl_xor(s2, 32, 64);
  float e2 = fmaxf(emax, __shfl_xor(emax, 16, 64));
  float emrow = fmaxf(e2, __shfl_xor(e2, 32, 64));

  // ---- stash partial state; merge halves in-block ----
  __syncthreads();    // all PV reads of staging region done
  float* sO  = (float*)smem;                       // [4 waves][16 rows][68]
  float* sML = (float*)(smem + 17408);             // [4 waves][16 rows][4]
  #pragma unroll
  for (int nf = 0; nf < 4; nf++)
    #pragma unroll
    for (int r = 0; r < 4; r++)
      sO[(w*16 + 4*g + r)*68 + nf*16 + i] = O[nf][r];
  if (lane < 16){
    float* p = sML + (w*16 + i)*4;
    p[0] = m; p[1] = lrow; p[2] = S1row; p[3] = emrow;
  }
  __syncthreads();

  if (w < 2){
    const float* p0 = sML + (w*16 + i)*4;        // half 0 (waves 0,1)
    const float* p1 = sML + ((w+2)*16 + i)*4;    // half 1 (waves 2,3)
    float m0 = p0[0], l0 = p0[1], s0v = p0[2], e0 = p0[3];
    float m1 = p1[0], l1 = p1[1], s1v = p1[2], e1 = p1[3];
    float M  = fmaxf(m0, m1);
    float a0 = exp2f(m0 - M), a1 = exp2f(m1 - M);
    float L   = a0*l0 + a1*l1;
    float S1c = a0*(s0v + (m0 - M)*l0) + a1*(s1v + (m1 - M)*l1);
    float emc = fmaxf(a0*e0, a1*e1);
    float inv = 1.0f / L;

    union { s16x8 v[2]; unsigned short u[16]; } ob;
    #pragma unroll
    for (int j4 = 0; j4 < 4; j4++){
      float4 x0 = *(const float4*)&sO[(w*16 + i)*68 + g*16 + j4*4];
      float4 x1 = *(const float4*)&sO[((w+2)*16 + i)*68 + g*16 + j4*4];
      ob.u[j4*4+0] = f2bf((a0*x0.x + a1*x1.x) * inv);
      ob.u[j4*4+1] = f2bf((a0*x0.y + a1*x1.y) * inv);
      ob.u[j4*4+2] = f2bf((a0*x0.z + a1*x1.z) * inv);
      ob.u[j4*4+3] = f2bf((a0*x0.w + a1*x1.w) * inv);
    }
    unsigned short* yp = yb + ((size_t)(b << 10) + q0 + w*16 + i) * 512 + h*64 + g*16;
    *(s16x8*)yp       = ob.v[0];
    *(s16x8*)(yp + 8) = ob.v[1];

    float ent = __logf(L) - LN2 * S1c * inv;
    float esum = (g == 0) ? ent : 0.f;
    float wmax = emc * inv;
    #pragma unroll
    for (int off = 1; off < 64; off <<= 1){
      esum += __shfl_xor(esum, off, 64);
      wmax = fmaxf(wmax, __shfl_xor(wmax, off, 64));
    }
    if (lane == 0){ sE[w] = esum; sMx[w] = wmax; }
  }
  __syncthreads();
  if (tid == 0){
    entp[blk] = sE[0] + sE[1];
    maxp[blk] = fmaxf(sMx[0], sMx[1]);
  }
}

// ---------------- GEMM2: out = y @ Wproj^T, 64x64 tile, grid 512 = 2/CU; block(0,0) finalizes ----------------
__global__ __launch_bounds__(256) void gemm_proj(
    const unsigned short* __restrict__ A,   // yb [4096][512]
    const unsigned short* __restrict__ Bt,  // wprojb [512][512]
    float* __restrict__ out,
    const float* __restrict__ entp, const float* __restrict__ maxp,
    float* __restrict__ scal)
{
  __shared__ __align__(16) unsigned short lA[64*32];
  __shared__ __align__(16) unsigned short lB[64*32];
  const int tid = threadIdx.x;
  const int lane = tid & 63;
  const int wid  = tid >> 6;
  const int i = lane & 15, g = lane >> 4;
  const int m0 = blockIdx.x * 64;
  const int n0 = blockIdx.y * 64;
  const int wr = wid >> 1, wc = wid & 1;   // wave tile 32 x 32
  const int K = 512;
  const int srA = tid >> 2;
  const int scc = (tid & 3) * 8;
  const unsigned short* ApS = A  + (size_t)(m0 + srA) * K + scc;
  const unsigned short* BpS = Bt + (size_t)(n0 + srA) * K + scc;
  unsigned short* lAs = lA + srA*32 + scc;
  unsigned short* lBs = lB + srA*32 + scc;

  f32x4 acc[2][2] = {};
  for (int k0 = 0; k0 < K; k0 += 32){
    gl16(ApS + k0, lAs);
    gl16(BpS + k0, lBs);
    __syncthreads();
    s16x8 aF[2], bF[2];
    #pragma unroll
    for (int mi = 0; mi < 2; mi++)
      aF[mi] = *(const s16x8*)(lA + (wr*32 + mi*16 + i)*32 + 8*g);
    #pragma unroll
    for (int ni = 0; ni < 2; ni++)
      bF[ni] = *(const s16x8*)(lB + (wc*32 + ni*16 + i)*32 + 8*g);
    #pragma unroll
    for (int mi = 0; mi < 2; mi++)
      #pragma unroll
      for (int ni = 0; ni < 2; ni++)
        acc[mi][ni] = MFMA16(aF[mi], bF[ni], acc[mi][ni], 0, 0, 0);
    __syncthreads();
  }
  #pragma unroll
  for (int mi = 0; mi < 2; mi++){
    #pragma unroll
    for (int r = 0; r < 4; r++){
      int row = m0 + wr*32 + mi*16 + 4*g + r;
      #pragma unroll
      for (int ni = 0; ni < 2; ni++){
        int col = n0 + wc*32 + ni*16 + i;
        out[(size_t)row * 512 + col] = acc[mi][ni][r];
      }
    }
  }

  // ---- fused finalize (stream-ordered after attn) ----
  if (blockIdx.x == 0 && blockIdx.y == 0 && tid < 64){
    float e = 0.f, mx = -1e30f;
    for (int j = tid; j < 1024; j += 64){
      e += entp[j];
      mx = fmaxf(mx, maxp[j]);
    }
    #pragma unroll
    for (int off = 1; off < 64; off <<= 1){
      e += __shfl_xor(e, off, 64);
      mx = fmaxf(mx, __shfl_xor(mx, off, 64));
    }
    if (tid == 0){
      scal[0] = e / 32768.0f;    // mean entropy over B*H*N rows
      scal[1] = mx;              // amax
      scal[2] = 1.0f / 1024.0f;  // amean (rows sum to 1)
    }
  }
}

extern "C" void kernel_launch(void* const* d_in, const int* in_sizes, int n_in,
                              void* d_out, int out_size, void* d_ws, size_t ws_size,
                              hipStream_t stream){
  const float* x     = (const float*)d_in[0];
  const float* Wqkv  = (const float*)d_in[1];
  const float* Wproj = (const float*)d_in[2];
  const float* table = (const float*)d_in[3];
  const int*   index = (const int*)d_in[4];   // unused: relpos index is analytic
  (void)index;
  float* out = (float*)d_out;
  char* ws = (char*)d_ws;

  unsigned short* xb     = (unsigned short*)(ws + 0);          //  4 MB
  unsigned short* wqkvb  = (unsigned short*)(ws + 4194304);    //  1.5 MB
  unsigned short* wprojb = (unsigned short*)(ws + 5767168);    //  0.5 MB
  unsigned short* qb     = (unsigned short*)(ws + 6291456);    //  4 MB
  unsigned short* kb     = (unsigned short*)(ws + 10485760);   //  4 MB
  unsigned short* vt2    = (unsigned short*)(ws + 14680064);   //  4 MB
  unsigned short* yb     = (unsigned short*)(ws + 18874368);   //  4 MB
  unsigned short* tableb = (unsigned short*)(ws + 23068672);   // 64 KB [8][4096]
  float* entp            = (float*)(ws + 39845888);            //  4 KB (1024)
  float* maxp            = (float*)(ws + 39849984);            //  4 KB (1024)
  unsigned short* vb     = (unsigned short*)(ws + 41943040);   //  4 MB (natural-layout V)

  cvt_all<<<3088, 256, 0, stream>>>(x, Wqkv, Wproj, table, xb, wqkvb, wprojb, tableb);
  gemm_qkv<<<dim3(64, 12), 256, 0, stream>>>(xb, wqkvb, qb, kb, vb);
  v_transpose<<<512, 256, 0, stream>>>(vb, vt2);
  attn<<<1024, 256, 0, stream>>>(qb, kb, vt2, tableb, yb, entp, maxp);
  gemm_proj<<<dim3(64, 8), 256, 0, stream>>>(yb, wprojb, out, entp, maxp, out + 2097152);
}